// Round 5
// baseline (801.258 us; speedup 1.0000x reference)
//
#include <hip/hip_runtime.h>
#include <cstdint>
#include <cstddef>

#define Nn 50000
#define Ne 800000
#define Ng 1024
#define NFd 32
#define Rr 4
#define Hd 64
#define Od 16
#define MAXD 10
#define NSEG (Nn * Rr)
#define SCAN_BLK ((NSEG + 255) / 256)
#define NB_MF 402                 // ceil((Nn + 128*11)/128)
#define NPAD128 (NB_MF * 128)     // 51456 >= 50000 + 11*127 worst-case padding
#define NB_RG ((Nn / 8 + 15) / 16)  // 391 blocks of 16 waves x 8 nodes

__device__ __forceinline__ float reluf(float v) { return v > 0.f ? v : 0.f; }

// ---- per-edge relation argmax -> segment id (tgt*R+rel) + segment histogram ----
__global__ void k_rel_seg(const float4* __restrict__ ea, const int* __restrict__ eidx,
                          int* __restrict__ seg, int* __restrict__ cnt) {
    int e = blockIdx.x * 256 + threadIdx.x;
    if (e >= Ne) return;
    float4 a = ea[e];
    int bi = 0; float bv = a.x;
    if (a.y > bv) { bv = a.y; bi = 1; }
    if (a.z > bv) { bv = a.z; bi = 2; }
    if (a.w > bv) { bv = a.w; bi = 3; }
    int s = eidx[Ne + e] * Rr + bi;
    seg[e] = s;
    atomicAdd(&cnt[s], 1);
}

// ---- 3-kernel exclusive scan over cnt[NSEG] -> off[NSEG+1] ----
__global__ void k_scan1(const int* __restrict__ cnt, int* __restrict__ off,
                        int* __restrict__ bsum) {
    __shared__ int s[256];
    int t = threadIdx.x;
    int idx = blockIdx.x * 256 + t;
    int v = (idx < NSEG) ? cnt[idx] : 0;
    s[t] = v;
    __syncthreads();
    #pragma unroll
    for (int o = 1; o < 256; o <<= 1) {
        int x = (t >= o) ? s[t - o] : 0;
        __syncthreads();
        s[t] += x;
        __syncthreads();
    }
    if (idx < NSEG) off[idx] = s[t] - v;            // exclusive
    if (t == 255) bsum[blockIdx.x] = s[255];
}

__global__ void k_scan2(int* __restrict__ bsum) {
    __shared__ int s[1024];
    int t = threadIdx.x;
    int v = (t < SCAN_BLK) ? bsum[t] : 0;
    s[t] = v;
    __syncthreads();
    #pragma unroll
    for (int o = 1; o < 1024; o <<= 1) {
        int x = (t >= o) ? s[t - o] : 0;
        __syncthreads();
        s[t] += x;
        __syncthreads();
    }
    if (t < SCAN_BLK) bsum[t] = s[t] - v;           // exclusive block bases
}

__global__ void k_scan3(int* __restrict__ off, const int* __restrict__ bsum,
                        int* __restrict__ fill) {
    int idx = blockIdx.x * 256 + threadIdx.x;
    if (idx == 0) off[NSEG] = Ne;
    if (idx >= NSEG) return;
    int v = off[idx] + bsum[blockIdx.x];
    off[idx] = v;
    fill[idx] = v;
}

// ---- scatter edges into segment-sorted order (store src only) ----
__global__ void k_scatter(const int* __restrict__ eidx, const int* __restrict__ seg,
                          int* __restrict__ fill, int* __restrict__ sorted_src) {
    int e = blockIdx.x * 256 + threadIdx.x;
    if (e >= Ne) return;
    int pos = atomicAdd(&fill[seg[e]], 1);
    sorted_src[pos] = eidx[e];
}

// ---- embedding lookup: wave per node; writes relu'd row (raw h0 never consumed) ----
__global__ void k_embed(const float* __restrict__ x, const float* __restrict__ emb,
                        float* __restrict__ h) {
    int wave = (blockIdx.x * 256 + threadIdx.x) >> 6;
    int lane = threadIdx.x & 63;
    if (wave >= Nn) return;
    float v = (lane < NFd) ? x[(size_t)wave * NFd + lane] : -1e30f;
    int idx = lane;
    #pragma unroll
    for (int off = 16; off >= 1; off >>= 1) {
        float ov = __shfl_down(v, off);
        int oi = __shfl_down(idx, off);
        if (ov > v || (ov == v && oi < idx)) { v = ov; idx = oi; }
    }
    idx = __shfl(idx, 0);
    h[(size_t)wave * Hd + lane] = reluf(emb[(size_t)idx * Hd + lane]);
}

// ---- degree bucketing from CSR offsets (LDS hist, 11 global atomics/block) ----
__global__ void k_bucket_count(const int* __restrict__ off, int* __restrict__ bcnt) {
    __shared__ int hist[16];
    if (threadIdx.x < 16) hist[threadIdx.x] = 0;
    __syncthreads();
    int n = blockIdx.x * 256 + threadIdx.x;
    if (n < Nn) {
        int d = min(off[n * Rr + Rr] - off[n * Rr], MAXD);
        atomicAdd(&hist[d], 1);
    }
    __syncthreads();
    if (threadIdx.x < 16) {
        int h = hist[threadIdx.x];
        if (h > 0) atomicAdd(&bcnt[threadIdx.x], h);
    }
}

__global__ void k_bucket_prefix(const int* __restrict__ bcnt, int* __restrict__ bbase) {
    if (threadIdx.x == 0 && blockIdx.x == 0) {
        int run = 0;
        for (int d = 0; d <= MAXD; d++) { bbase[d] = run; run += (bcnt[d] + 127) & ~127; }
    }
}

__global__ void k_bucket_scatter(const int* __restrict__ off, const int* __restrict__ bbase,
                                 int* __restrict__ bfill, int* __restrict__ order) {
    __shared__ int hist[16];
    __shared__ int base[16];
    if (threadIdx.x < 16) hist[threadIdx.x] = 0;
    __syncthreads();
    int n = blockIdx.x * 256 + threadIdx.x;
    int d = 0, rank = 0;
    bool valid = (n < Nn);
    if (valid) {
        d = min(off[n * Rr + Rr] - off[n * Rr], MAXD);
        rank = atomicAdd(&hist[d], 1);
    }
    __syncthreads();
    if (threadIdx.x < 16) {
        int h = hist[threadIdx.x];
        base[threadIdx.x] = (h > 0) ? atomicAdd(&bfill[threadIdx.x], h) : 0;
    }
    __syncthreads();
    if (valid) order[bbase[d] + base[d] + rank] = n | (d << 20);
}

// ---- RGCN: segmented MEAN of h[src] per (tgt,rel); wave per segment (h pre-relu'd) ----
__global__ void k_rgcn_agg(const float* __restrict__ hin, const int* __restrict__ off,
                           const int* __restrict__ sorted_src, float* __restrict__ agg) {
    int s = __builtin_amdgcn_readfirstlane((blockIdx.x * 256 + threadIdx.x) >> 6);
    int lane = threadIdx.x & 63;
    if (s >= NSEG) return;
    int s0 = __builtin_amdgcn_readfirstlane(off[s]);
    int s1 = __builtin_amdgcn_readfirstlane(off[s + 1]);
    float sum = 0.f;
    for (int e = s0; e < s1; e++) {
        int src = __builtin_amdgcn_readfirstlane(sorted_src[e]);
        sum += hin[(size_t)src * Hd + lane];
    }
    float inv = (s1 > s0) ? 1.f / (float)(s1 - s0) : 0.f;
    agg[(size_t)s * Hd + lane] = sum * inv;
}

// ---- RGCN transform: out = relu(sum_r mean_r @ W[r] + h @ Wroot + b) ----
// 1024-thread block stages all 5 weight matrices (80 KB) into LDS once;
// 16 waves x 8 nodes/wave keep TLP high (R4 lesson: 26% occ killed it).
__global__ __launch_bounds__(1024) void k_rgcn_xform(
        const float* __restrict__ hin, const float* __restrict__ agg,
        const float* __restrict__ W, const float* __restrict__ Wroot,
        const float* __restrict__ bias, float* __restrict__ hout) {
    __shared__ float wlds[5 * Hd * Hd];            // 80 KB: [0..4095]=Wroot, then W[r]
    int tid = threadIdx.x;
    {
        float4* dst = (float4*)wlds;
        dst[tid] = ((const float4*)Wroot)[tid];    // 4096 floats
        float4* d1 = (float4*)(wlds + Hd * Hd);
        const float4* s1 = (const float4*)W;       // 16384 floats
        #pragma unroll
        for (int j = 0; j < 4; j++) d1[j * 1024 + tid] = s1[j * 1024 + tid];
    }
    __syncthreads();
    int wv = tid >> 6, lane = tid & 63;
    int wave = __builtin_amdgcn_readfirstlane(blockIdx.x * 16 + wv);
    int n0 = wave * 8;
    if (n0 >= Nn) return;
    float bj = bias[lane];
    float acc[8];
    #pragma unroll
    for (int i = 0; i < 8; i++) acc[i] = bj;
    // root term (hin pre-relu'd)
    const float* hb = hin + (size_t)n0 * Hd;
    for (int kc = 0; kc < Hd; kc += 4) {
        float w0 = wlds[(kc + 0) * Hd + lane];
        float w1 = wlds[(kc + 1) * Hd + lane];
        float w2 = wlds[(kc + 2) * Hd + lane];
        float w3 = wlds[(kc + 3) * Hd + lane];
        #pragma unroll
        for (int i = 0; i < 8; i++) {
            const float4 iv = *(const float4*)(hb + i * Hd + kc);
            acc[i] += iv.x * w0 + iv.y * w1 + iv.z * w2 + iv.w * w3;
        }
    }
    // relation terms (agg already holds the mean)
    const float* ab = agg + (size_t)n0 * Rr * Hd;
    for (int r = 0; r < Rr; r++) {
        const float* wp = wlds + (1 + r) * Hd * Hd;
        for (int kc = 0; kc < Hd; kc += 4) {
            float w0 = wp[(kc + 0) * Hd + lane];
            float w1 = wp[(kc + 1) * Hd + lane];
            float w2 = wp[(kc + 2) * Hd + lane];
            float w3 = wp[(kc + 3) * Hd + lane];
            #pragma unroll
            for (int i = 0; i < 8; i++) {
                const float4 iv = *(const float4*)(ab + ((size_t)i * Rr + r) * Hd + kc);
                acc[i] += iv.x * w0 + iv.y * w1 + iv.z * w2 + iv.w * w3;
            }
        }
    }
    #pragma unroll
    for (int i = 0; i < 8; i++) hout[(size_t)(n0 + i) * Hd + lane] = reluf(acc[i]);
}

// ---- MFConv: segmented SUM of h[src] per tgt (h already relu'd); wave per node ----
__global__ void k_mf_agg(const float* __restrict__ hin, const int* __restrict__ off,
                         const int* __restrict__ sorted_src, float* __restrict__ agg2) {
    int n = __builtin_amdgcn_readfirstlane((blockIdx.x * 256 + threadIdx.x) >> 6);
    int lane = threadIdx.x & 63;
    if (n >= Nn) return;
    int s0 = __builtin_amdgcn_readfirstlane(off[n * Rr]);
    int s1 = __builtin_amdgcn_readfirstlane(off[n * Rr + Rr]);
    float sum = 0.f;
    for (int e = s0; e < s1; e++) {
        int src = __builtin_amdgcn_readfirstlane(sorted_src[e]);
        sum += hin[(size_t)src * Hd + lane];
    }
    agg2[(size_t)n * Hd + lane] = sum;
}

// ---- MFConv transform: bucket-aligned 128-node blocks; Wl[d]+Wr[d] (32 KB) in LDS ----
__global__ __launch_bounds__(1024) void k_mf_xform(
        const float* __restrict__ hin, const float* __restrict__ agg2,
        const int* __restrict__ order, const float* __restrict__ Wl,
        const float* __restrict__ bl, const float* __restrict__ Wr,
        float* __restrict__ hout, int relu_out) {
    __shared__ float wlds[2 * Hd * Hd];            // 32 KB
    __shared__ int d_sh;
    int tid = threadIdx.x;
    if (tid == 0) d_sh = -1;
    __syncthreads();
    int g0 = blockIdx.x * 128;
    if (tid < 128) {
        int e = order[g0 + tid];
        if (e >= 0) atomicMax(&d_sh, e >> 20);     // all valid entries share one d
    }
    __syncthreads();
    int d = d_sh;
    if (d >= 0) {
        ((float4*)wlds)[tid] = ((const float4*)(Wl + (size_t)d * Hd * Hd))[tid];
        ((float4*)(wlds + Hd * Hd))[tid] = ((const float4*)(Wr + (size_t)d * Hd * Hd))[tid];
    }
    __syncthreads();
    if (d < 0) return;
    int wv = tid >> 6, lane = tid & 63;
    int slot0 = __builtin_amdgcn_readfirstlane(g0 + wv * 8);
    int ent[8];
    #pragma unroll
    for (int i = 0; i < 8; i++) ent[i] = order[slot0 + i];
    int n[8];
    #pragma unroll
    for (int i = 0; i < 8; i++) n[i] = (ent[i] >= 0) ? (ent[i] & 0xFFFFF) : 0;
    float acc[8];
    #pragma unroll
    for (int i = 0; i < 8; i++) acc[i] = 0.f;
    for (int kc = 0; kc < Hd; kc += 4) {
        float a0 = wlds[(kc + 0) * Hd + lane];
        float a1 = wlds[(kc + 1) * Hd + lane];
        float a2 = wlds[(kc + 2) * Hd + lane];
        float a3 = wlds[(kc + 3) * Hd + lane];
        float b0 = wlds[Hd * Hd + (kc + 0) * Hd + lane];
        float b1 = wlds[Hd * Hd + (kc + 1) * Hd + lane];
        float b2 = wlds[Hd * Hd + (kc + 2) * Hd + lane];
        float b3 = wlds[Hd * Hd + (kc + 3) * Hd + lane];
        #pragma unroll
        for (int i = 0; i < 8; i++) {
            const float4 av = *(const float4*)(agg2 + (size_t)n[i] * Hd + kc);
            const float4 hv = *(const float4*)(hin + (size_t)n[i] * Hd + kc);
            acc[i] += av.x * a0 + av.y * a1 + av.z * a2 + av.w * a3
                    + hv.x * b0 + hv.y * b1 + hv.z * b2 + hv.w * b3;
        }
    }
    float bb = bl[d * Hd + lane];
    #pragma unroll
    for (int i = 0; i < 8; i++)
        if (ent[i] >= 0) {
            float v = acc[i] + bb;
            hout[(size_t)n[i] * Hd + lane] = relu_out ? reluf(v) : v;
        }
}

// ---- global add pool (batch_idx is sorted -> mostly single fused atomic) ----
__global__ void k_pool(const float* __restrict__ h, const int* __restrict__ batch,
                       float* __restrict__ g) {
    int wave = __builtin_amdgcn_readfirstlane((blockIdx.x * 256 + threadIdx.x) >> 6);
    int lane = threadIdx.x & 63;
    int n0 = wave * 4;
    if (n0 >= Nn) return;
    int b0 = batch[n0], b1 = batch[n0 + 1], b2 = batch[n0 + 2], b3 = batch[n0 + 3];
    float v0 = h[(size_t)n0 * Hd + lane];
    float v1 = h[(size_t)(n0 + 1) * Hd + lane];
    float v2 = h[(size_t)(n0 + 2) * Hd + lane];
    float v3 = h[(size_t)(n0 + 3) * Hd + lane];
    if (b0 == b1 && b0 == b2 && b0 == b3) {
        unsafeAtomicAdd(&g[(size_t)b0 * Hd + lane], v0 + v1 + v2 + v3);
    } else {
        unsafeAtomicAdd(&g[(size_t)b0 * Hd + lane], v0);
        unsafeAtomicAdd(&g[(size_t)b1 * Hd + lane], v1);
        unsafeAtomicAdd(&g[(size_t)b2 * Hd + lane], v2);
        unsafeAtomicAdd(&g[(size_t)b3 * Hd + lane], v3);
    }
}

// ---- head: relu(g@lin1+b1)@lin2+b2, one wave per graph ----
__global__ void k_head(const float* __restrict__ g, const float* __restrict__ w1,
                       const float* __restrict__ b1, const float* __restrict__ w2,
                       const float* __restrict__ b2, float* __restrict__ out) {
    __shared__ float t[4][Hd];
    int wv = threadIdx.x >> 6;
    int lane = threadIdx.x & 63;
    int gi = blockIdx.x * 4 + wv;
    float acc = b1[lane];
    for (int k = 0; k < Hd; k++) acc += g[(size_t)gi * Hd + k] * w1[k * Hd + lane];
    t[wv][lane] = reluf(acc);
    __syncthreads();
    if (lane < Od) {
        float o = b2[lane];
        for (int k = 0; k < Hd; k++) o += t[wv][k] * w2[k * Od + lane];
        out[(size_t)gi * Od + lane] = o;
    }
}

extern "C" void kernel_launch(void* const* d_in, const int* in_sizes, int n_in,
                              void* d_out, int out_size, void* d_ws, size_t ws_size,
                              hipStream_t stream) {
    const float* x      = (const float*)d_in[0];
    const float* ea     = (const float*)d_in[1];
    const int*   eidx   = (const int*)d_in[2];
    const int*   batch  = (const int*)d_in[3];
    const float* emb    = (const float*)d_in[4];
    const float* lin1_w = (const float*)d_in[5];
    const float* lin1_b = (const float*)d_in[6];
    const float* lin2_w = (const float*)d_in[7];
    const float* lin2_b = (const float*)d_in[8];
    const float* rgcn_w[2]    = {(const float*)d_in[9],  (const float*)d_in[15]};
    const float* rgcn_root[2] = {(const float*)d_in[10], (const float*)d_in[16]};
    const float* rgcn_b[2]    = {(const float*)d_in[11], (const float*)d_in[17]};
    const float* mf_wl[2]     = {(const float*)d_in[12], (const float*)d_in[18]};
    const float* mf_bl[2]     = {(const float*)d_in[13], (const float*)d_in[19]};
    const float* mf_wr[2]     = {(const float*)d_in[14], (const float*)d_in[20]};

    char* p = (char*)d_ws;
    float* h0   = (float*)p; p += sizeof(float) * (size_t)Nn * Hd;
    float* h1   = (float*)p; p += sizeof(float) * (size_t)Nn * Hd;
    float* agg  = (float*)p; p += sizeof(float) * (size_t)NSEG * Hd;
    float* gbuf = (float*)p; p += sizeof(float) * (size_t)Ng * Hd;
    int* seg    = (int*)p;   p += sizeof(int) * (size_t)Ne;
    int* ssrc   = (int*)p;   p += sizeof(int) * (size_t)Ne;
    int* cnt    = (int*)p;   p += sizeof(int) * (size_t)NSEG;   // contiguous with bcnt/bfill
    int* bcnt   = (int*)p;   p += sizeof(int) * 16;
    int* bfill  = (int*)p;   p += sizeof(int) * 16;
    int* off    = (int*)p;   p += sizeof(int) * (size_t)(NSEG + 1);
    int* fill   = (int*)p;   p += sizeof(int) * (size_t)NSEG;
    int* bsum   = (int*)p;   p += sizeof(int) * 1024;
    int* bbase  = (int*)p;   p += sizeof(int) * 16;
    int* order  = (int*)p;   p += sizeof(int) * (size_t)NPAD128;

    hipMemsetAsync(cnt, 0, sizeof(int) * ((size_t)NSEG + 32), stream);
    hipMemsetAsync(order, 0xFF, sizeof(int) * (size_t)NPAD128, stream);
    hipMemsetAsync(gbuf, 0, sizeof(float) * (size_t)Ng * Hd, stream);

    k_rel_seg<<<Ne / 256, 256, 0, stream>>>((const float4*)ea, eidx, seg, cnt);
    k_scan1<<<SCAN_BLK, 256, 0, stream>>>(cnt, off, bsum);
    k_scan2<<<1, 1024, 0, stream>>>(bsum);
    k_scan3<<<SCAN_BLK, 256, 0, stream>>>(off, bsum, fill);
    k_scatter<<<Ne / 256, 256, 0, stream>>>(eidx, seg, fill, ssrc);
    k_embed<<<Nn / 4, 256, 0, stream>>>(x, emb, h0);
    k_bucket_count<<<(Nn + 255) / 256, 256, 0, stream>>>(off, bcnt);
    k_bucket_prefix<<<1, 64, 0, stream>>>(bcnt, bbase);
    k_bucket_scatter<<<(Nn + 255) / 256, 256, 0, stream>>>(off, bbase, bfill, order);

    float* hin = h0;
    float* hout = h1;
    for (int b = 0; b < 2; b++) {
        k_rgcn_agg<<<NSEG / 4, 256, 0, stream>>>(hin, off, ssrc, agg);
        k_rgcn_xform<<<NB_RG, 1024, 0, stream>>>(hin, agg, rgcn_w[b], rgcn_root[b],
                                                 rgcn_b[b], hout);
        k_mf_agg<<<Nn / 4, 256, 0, stream>>>(hout, off, ssrc, agg);
        k_mf_xform<<<NB_MF, 1024, 0, stream>>>(hout, agg, order, mf_wl[b],
                                               mf_bl[b], mf_wr[b], hin,
                                               b == 0 ? 1 : 0);
        // block output is back in hin for the next block (relu'd for b=0, raw for b=1)
    }
    k_pool<<<Nn / 16, 256, 0, stream>>>(hin, batch, gbuf);
    k_head<<<Ng / 4, 256, 0, stream>>>(gbuf, lin1_w, lin1_b, lin2_w, lin2_b, (float*)d_out);
}

// Round 6
// 611.244 us; speedup vs baseline: 1.3109x; 1.3109x over previous
//
#include <hip/hip_runtime.h>
#include <cstdint>
#include <cstddef>

#define Nn 50000
#define Ne 800000
#define Ng 1024
#define NFd 32
#define Rr 4
#define Hd 64
#define Od 16
#define MAXD 10
#define NSEG (Nn * Rr)
#define SCAN_BLK ((NSEG + 255) / 256)
#define NB_MF ((Nn + 32 * (MAXD + 1) + 31) / 32)   // 1574 blocks of 32 slots
#define NPAD32 (NB_MF * 32)
#define NB_RG ((Nn / 8 + 3) / 4)                   // 1563 blocks of 4 waves x 8 nodes

__device__ __forceinline__ float reluf(float v) { return v > 0.f ? v : 0.f; }

// ---- per-edge relation argmax -> segment id (tgt*R+rel) + segment histogram ----
__global__ void k_rel_seg(const float4* __restrict__ ea, const int* __restrict__ eidx,
                          int* __restrict__ seg, int* __restrict__ cnt) {
    int e = blockIdx.x * 256 + threadIdx.x;
    if (e >= Ne) return;
    float4 a = ea[e];
    int bi = 0; float bv = a.x;
    if (a.y > bv) { bv = a.y; bi = 1; }
    if (a.z > bv) { bv = a.z; bi = 2; }
    if (a.w > bv) { bv = a.w; bi = 3; }
    int s = eidx[Ne + e] * Rr + bi;
    seg[e] = s;
    atomicAdd(&cnt[s], 1);
}

// ---- 3-kernel exclusive scan over cnt[NSEG] -> off[NSEG+1] ----
__global__ void k_scan1(const int* __restrict__ cnt, int* __restrict__ off,
                        int* __restrict__ bsum) {
    __shared__ int s[256];
    int t = threadIdx.x;
    int idx = blockIdx.x * 256 + t;
    int v = (idx < NSEG) ? cnt[idx] : 0;
    s[t] = v;
    __syncthreads();
    #pragma unroll
    for (int o = 1; o < 256; o <<= 1) {
        int x = (t >= o) ? s[t - o] : 0;
        __syncthreads();
        s[t] += x;
        __syncthreads();
    }
    if (idx < NSEG) off[idx] = s[t] - v;            // exclusive
    if (t == 255) bsum[blockIdx.x] = s[255];
}

__global__ void k_scan2(int* __restrict__ bsum) {
    __shared__ int s[1024];
    int t = threadIdx.x;
    int v = (t < SCAN_BLK) ? bsum[t] : 0;
    s[t] = v;
    __syncthreads();
    #pragma unroll
    for (int o = 1; o < 1024; o <<= 1) {
        int x = (t >= o) ? s[t - o] : 0;
        __syncthreads();
        s[t] += x;
        __syncthreads();
    }
    if (t < SCAN_BLK) bsum[t] = s[t] - v;           // exclusive block bases
}

__global__ void k_scan3(int* __restrict__ off, const int* __restrict__ bsum,
                        int* __restrict__ fill) {
    int idx = blockIdx.x * 256 + threadIdx.x;
    if (idx == 0) off[NSEG] = Ne;
    if (idx >= NSEG) return;
    int v = off[idx] + bsum[blockIdx.x];
    off[idx] = v;
    fill[idx] = v;
}

// ---- scatter edges into segment-sorted order (store src only) ----
__global__ void k_scatter(const int* __restrict__ eidx, const int* __restrict__ seg,
                          int* __restrict__ fill, int* __restrict__ sorted_src) {
    int e = blockIdx.x * 256 + threadIdx.x;
    if (e >= Ne) return;
    int pos = atomicAdd(&fill[seg[e]], 1);
    sorted_src[pos] = eidx[e];
}

// ---- embedding lookup: wave per node; writes relu'd row ----
__global__ void k_embed(const float* __restrict__ x, const float* __restrict__ emb,
                        float* __restrict__ h) {
    int wave = (blockIdx.x * 256 + threadIdx.x) >> 6;
    int lane = threadIdx.x & 63;
    if (wave >= Nn) return;
    float v = (lane < NFd) ? x[(size_t)wave * NFd + lane] : -1e30f;
    int idx = lane;
    #pragma unroll
    for (int off = 16; off >= 1; off >>= 1) {
        float ov = __shfl_down(v, off);
        int oi = __shfl_down(idx, off);
        if (ov > v || (ov == v && oi < idx)) { v = ov; idx = oi; }
    }
    idx = __shfl(idx, 0);
    h[(size_t)wave * Hd + lane] = reluf(emb[(size_t)idx * Hd + lane]);
}

// ---- degree bucketing from CSR offsets (LDS hist, 11 global atomics/block) ----
__global__ void k_bucket_count(const int* __restrict__ off, int* __restrict__ bcnt) {
    __shared__ int hist[16];
    if (threadIdx.x < 16) hist[threadIdx.x] = 0;
    __syncthreads();
    int n = blockIdx.x * 256 + threadIdx.x;
    if (n < Nn) {
        int d = min(off[n * Rr + Rr] - off[n * Rr], MAXD);
        atomicAdd(&hist[d], 1);
    }
    __syncthreads();
    if (threadIdx.x < 16) {
        int h = hist[threadIdx.x];
        if (h > 0) atomicAdd(&bcnt[threadIdx.x], h);
    }
}

__global__ void k_bucket_prefix(const int* __restrict__ bcnt, int* __restrict__ bbase) {
    if (threadIdx.x == 0 && blockIdx.x == 0) {
        int run = 0;
        for (int d = 0; d <= MAXD; d++) { bbase[d] = run; run += (bcnt[d] + 31) & ~31; }
    }
}

__global__ void k_bucket_scatter(const int* __restrict__ off, const int* __restrict__ bbase,
                                 int* __restrict__ bfill, int* __restrict__ order) {
    __shared__ int hist[16];
    __shared__ int base[16];
    if (threadIdx.x < 16) hist[threadIdx.x] = 0;
    __syncthreads();
    int n = blockIdx.x * 256 + threadIdx.x;
    int d = 0, rank = 0;
    bool valid = (n < Nn);
    if (valid) {
        d = min(off[n * Rr + Rr] - off[n * Rr], MAXD);
        rank = atomicAdd(&hist[d], 1);
    }
    __syncthreads();
    if (threadIdx.x < 16) {
        int h = hist[threadIdx.x];
        base[threadIdx.x] = (h > 0) ? atomicAdd(&bfill[threadIdx.x], h) : 0;
    }
    __syncthreads();
    if (valid) order[bbase[d] + base[d] + rank] = n | (d << 20);
}

// ---- FUSED RGCN layer: gather means + transform in one kernel ----
// Wave owns 8 nodes; per-wave LDS region does row->k-broadcast transform.
// No barriers (no cross-wave LDS sharing). Weights stream from L2 (hot).
__global__ __launch_bounds__(256) void k_rgcn_fused(
        const float* __restrict__ hin, const int* __restrict__ off,
        const int* __restrict__ ssrc, const float* __restrict__ W,
        const float* __restrict__ Wroot, const float* __restrict__ bias,
        float* __restrict__ hout) {
    __shared__ float lds[4][2][8][Hd];              // 16 KB: [wave][root|mean][node][k]
    int tid = threadIdx.x;
    int wv = tid >> 6, lane = tid & 63;
    int wave = __builtin_amdgcn_readfirstlane(blockIdx.x * 4 + wv);
    int n0 = wave * 8;
    if (n0 >= Nn) return;
    float* rootb = &lds[wv][0][0][0];
    float* meanb = &lds[wv][1][0][0];
    float bj = bias[lane];
    float acc[8];
    #pragma unroll
    for (int i = 0; i < 8; i++) {
        acc[i] = bj;
        rootb[i * Hd + lane] = hin[(size_t)(n0 + i) * Hd + lane];
    }
    // root matmul
    for (int kc = 0; kc < Hd; kc += 4) {
        float w0 = Wroot[(kc + 0) * Hd + lane];
        float w1 = Wroot[(kc + 1) * Hd + lane];
        float w2 = Wroot[(kc + 2) * Hd + lane];
        float w3 = Wroot[(kc + 3) * Hd + lane];
        #pragma unroll
        for (int i = 0; i < 8; i++) {
            const float4 iv = *(const float4*)(rootb + i * Hd + kc);
            acc[i] += iv.x * w0 + iv.y * w1 + iv.z * w2 + iv.w * w3;
        }
    }
    // relations: gather mean rows into LDS, then matmul
    for (int r = 0; r < Rr; r++) {
        #pragma unroll
        for (int i = 0; i < 8; i++) {
            int n = n0 + i;
            int s0 = off[n * Rr + r];
            int s1 = off[n * Rr + r + 1];
            float sum = 0.f;
            int e = s0;
            for (; e + 4 <= s1; e += 4) {
                const int4 s4 = *(const int4*)(ssrc + e);   // uniform -> scalar load
                sum += hin[(size_t)s4.x * Hd + lane] + hin[(size_t)s4.y * Hd + lane]
                     + hin[(size_t)s4.z * Hd + lane] + hin[(size_t)s4.w * Hd + lane];
            }
            for (; e < s1; e++) sum += hin[(size_t)ssrc[e] * Hd + lane];
            float inv = (s1 > s0) ? 1.f / (float)(s1 - s0) : 0.f;
            meanb[i * Hd + lane] = sum * inv;
        }
        const float* Wp = W + (size_t)r * Hd * Hd;
        for (int kc = 0; kc < Hd; kc += 4) {
            float w0 = Wp[(kc + 0) * Hd + lane];
            float w1 = Wp[(kc + 1) * Hd + lane];
            float w2 = Wp[(kc + 2) * Hd + lane];
            float w3 = Wp[(kc + 3) * Hd + lane];
            #pragma unroll
            for (int i = 0; i < 8; i++) {
                const float4 iv = *(const float4*)(meanb + i * Hd + kc);
                acc[i] += iv.x * w0 + iv.y * w1 + iv.z * w2 + iv.w * w3;
            }
        }
    }
    #pragma unroll
    for (int i = 0; i < 8; i++) hout[(size_t)(n0 + i) * Hd + lane] = reluf(acc[i]);
}

// ---- FUSED MFConv layer: gather sum + degree-bucketed transform ----
// Buckets 32-aligned so each 8-node wave shares one degree d.
__global__ __launch_bounds__(256) void k_mf_fused(
        const float* __restrict__ hin, const int* __restrict__ off,
        const int* __restrict__ ssrc, const int* __restrict__ order,
        const float* __restrict__ Wl, const float* __restrict__ bl,
        const float* __restrict__ Wr, float* __restrict__ hout, int relu_out) {
    __shared__ float lds[4][2][8][Hd];              // 16 KB
    int tid = threadIdx.x;
    int wv = tid >> 6, lane = tid & 63;
    int slot0 = __builtin_amdgcn_readfirstlane(blockIdx.x * 32 + wv * 8);
    int ent[8];
    #pragma unroll
    for (int i = 0; i < 8; i++) ent[i] = order[slot0 + i];
    int d = -1;
    #pragma unroll
    for (int i = 7; i >= 0; i--) if (ent[i] >= 0) d = ent[i] >> 20;
    if (d < 0) return;
    int n[8];
    #pragma unroll
    for (int i = 0; i < 8; i++) n[i] = (ent[i] >= 0) ? (ent[i] & 0xFFFFF) : 0;
    float* rootb = &lds[wv][0][0][0];
    float* sumb  = &lds[wv][1][0][0];
    #pragma unroll
    for (int i = 0; i < 8; i++) {
        rootb[i * Hd + lane] = hin[(size_t)n[i] * Hd + lane];
        int s0 = off[n[i] * Rr];
        int s1 = off[n[i] * Rr + Rr];
        float sum = 0.f;
        int e = s0;
        for (; e + 4 <= s1; e += 4) {
            const int4 s4 = *(const int4*)(ssrc + e);
            sum += hin[(size_t)s4.x * Hd + lane] + hin[(size_t)s4.y * Hd + lane]
                 + hin[(size_t)s4.z * Hd + lane] + hin[(size_t)s4.w * Hd + lane];
        }
        for (; e < s1; e++) sum += hin[(size_t)ssrc[e] * Hd + lane];
        sumb[i * Hd + lane] = sum;
    }
    const float* wl = Wl + (size_t)d * Hd * Hd;
    const float* wr = Wr + (size_t)d * Hd * Hd;
    float acc[8];
    #pragma unroll
    for (int i = 0; i < 8; i++) acc[i] = 0.f;
    for (int kc = 0; kc < Hd; kc += 4) {
        float a0 = wl[(kc + 0) * Hd + lane];
        float a1 = wl[(kc + 1) * Hd + lane];
        float a2 = wl[(kc + 2) * Hd + lane];
        float a3 = wl[(kc + 3) * Hd + lane];
        float b0 = wr[(kc + 0) * Hd + lane];
        float b1 = wr[(kc + 1) * Hd + lane];
        float b2 = wr[(kc + 2) * Hd + lane];
        float b3 = wr[(kc + 3) * Hd + lane];
        #pragma unroll
        for (int i = 0; i < 8; i++) {
            const float4 av = *(const float4*)(sumb + i * Hd + kc);
            const float4 hv = *(const float4*)(rootb + i * Hd + kc);
            acc[i] += av.x * a0 + av.y * a1 + av.z * a2 + av.w * a3
                    + hv.x * b0 + hv.y * b1 + hv.z * b2 + hv.w * b3;
        }
    }
    float bb = bl[d * Hd + lane];
    #pragma unroll
    for (int i = 0; i < 8; i++)
        if (ent[i] >= 0) {
            float v = acc[i] + bb;
            hout[(size_t)n[i] * Hd + lane] = relu_out ? reluf(v) : v;
        }
}

// ---- global add pool (batch_idx is sorted -> mostly single fused atomic) ----
__global__ void k_pool(const float* __restrict__ h, const int* __restrict__ batch,
                       float* __restrict__ g) {
    int wave = __builtin_amdgcn_readfirstlane((blockIdx.x * 256 + threadIdx.x) >> 6);
    int lane = threadIdx.x & 63;
    int n0 = wave * 4;
    if (n0 >= Nn) return;
    int b0 = batch[n0], b1 = batch[n0 + 1], b2 = batch[n0 + 2], b3 = batch[n0 + 3];
    float v0 = h[(size_t)n0 * Hd + lane];
    float v1 = h[(size_t)(n0 + 1) * Hd + lane];
    float v2 = h[(size_t)(n0 + 2) * Hd + lane];
    float v3 = h[(size_t)(n0 + 3) * Hd + lane];
    if (b0 == b1 && b0 == b2 && b0 == b3) {
        unsafeAtomicAdd(&g[(size_t)b0 * Hd + lane], v0 + v1 + v2 + v3);
    } else {
        unsafeAtomicAdd(&g[(size_t)b0 * Hd + lane], v0);
        unsafeAtomicAdd(&g[(size_t)b1 * Hd + lane], v1);
        unsafeAtomicAdd(&g[(size_t)b2 * Hd + lane], v2);
        unsafeAtomicAdd(&g[(size_t)b3 * Hd + lane], v3);
    }
}

// ---- head: relu(g@lin1+b1)@lin2+b2, one wave per graph ----
__global__ void k_head(const float* __restrict__ g, const float* __restrict__ w1,
                       const float* __restrict__ b1, const float* __restrict__ w2,
                       const float* __restrict__ b2, float* __restrict__ out) {
    __shared__ float t[4][Hd];
    int wv = threadIdx.x >> 6;
    int lane = threadIdx.x & 63;
    int gi = blockIdx.x * 4 + wv;
    float acc = b1[lane];
    for (int k = 0; k < Hd; k++) acc += g[(size_t)gi * Hd + k] * w1[k * Hd + lane];
    t[wv][lane] = reluf(acc);
    __syncthreads();
    if (lane < Od) {
        float o = b2[lane];
        for (int k = 0; k < Hd; k++) o += t[wv][k] * w2[k * Od + lane];
        out[(size_t)gi * Od + lane] = o;
    }
}

extern "C" void kernel_launch(void* const* d_in, const int* in_sizes, int n_in,
                              void* d_out, int out_size, void* d_ws, size_t ws_size,
                              hipStream_t stream) {
    const float* x      = (const float*)d_in[0];
    const float* ea     = (const float*)d_in[1];
    const int*   eidx   = (const int*)d_in[2];
    const int*   batch  = (const int*)d_in[3];
    const float* emb    = (const float*)d_in[4];
    const float* lin1_w = (const float*)d_in[5];
    const float* lin1_b = (const float*)d_in[6];
    const float* lin2_w = (const float*)d_in[7];
    const float* lin2_b = (const float*)d_in[8];
    const float* rgcn_w[2]    = {(const float*)d_in[9],  (const float*)d_in[15]};
    const float* rgcn_root[2] = {(const float*)d_in[10], (const float*)d_in[16]};
    const float* rgcn_b[2]    = {(const float*)d_in[11], (const float*)d_in[17]};
    const float* mf_wl[2]     = {(const float*)d_in[12], (const float*)d_in[18]};
    const float* mf_bl[2]     = {(const float*)d_in[13], (const float*)d_in[19]};
    const float* mf_wr[2]     = {(const float*)d_in[14], (const float*)d_in[20]};

    char* p = (char*)d_ws;
    float* h0   = (float*)p; p += sizeof(float) * (size_t)Nn * Hd;
    float* h1   = (float*)p; p += sizeof(float) * (size_t)Nn * Hd;
    float* gbuf = (float*)p; p += sizeof(float) * (size_t)Ng * Hd;
    int* seg    = (int*)p;   p += sizeof(int) * (size_t)Ne;
    int* ssrc   = (int*)p;   p += sizeof(int) * (size_t)Ne;
    int* cnt    = (int*)p;   p += sizeof(int) * (size_t)NSEG;   // contiguous with bcnt/bfill
    int* bcnt   = (int*)p;   p += sizeof(int) * 16;
    int* bfill  = (int*)p;   p += sizeof(int) * 16;
    int* off    = (int*)p;   p += sizeof(int) * (size_t)(NSEG + 1);
    int* fill   = (int*)p;   p += sizeof(int) * (size_t)NSEG;
    int* bsum   = (int*)p;   p += sizeof(int) * 1024;
    int* bbase  = (int*)p;   p += sizeof(int) * 16;
    int* order  = (int*)p;   p += sizeof(int) * (size_t)NPAD32;

    hipMemsetAsync(cnt, 0, sizeof(int) * ((size_t)NSEG + 32), stream);
    hipMemsetAsync(order, 0xFF, sizeof(int) * (size_t)NPAD32, stream);
    hipMemsetAsync(gbuf, 0, sizeof(float) * (size_t)Ng * Hd, stream);

    k_rel_seg<<<Ne / 256, 256, 0, stream>>>((const float4*)ea, eidx, seg, cnt);
    k_scan1<<<SCAN_BLK, 256, 0, stream>>>(cnt, off, bsum);
    k_scan2<<<1, 1024, 0, stream>>>(bsum);
    k_scan3<<<SCAN_BLK, 256, 0, stream>>>(off, bsum, fill);
    k_scatter<<<Ne / 256, 256, 0, stream>>>(eidx, seg, fill, ssrc);
    k_embed<<<Nn / 4, 256, 0, stream>>>(x, emb, h0);
    k_bucket_count<<<(Nn + 255) / 256, 256, 0, stream>>>(off, bcnt);
    k_bucket_prefix<<<1, 64, 0, stream>>>(bcnt, bbase);
    k_bucket_scatter<<<(Nn + 255) / 256, 256, 0, stream>>>(off, bbase, bfill, order);

    float* hin = h0;
    float* hout = h1;
    for (int b = 0; b < 2; b++) {
        k_rgcn_fused<<<NB_RG, 256, 0, stream>>>(hin, off, ssrc, rgcn_w[b], rgcn_root[b],
                                                rgcn_b[b], hout);
        k_mf_fused<<<NB_MF, 256, 0, stream>>>(hout, off, ssrc, order, mf_wl[b],
                                              mf_bl[b], mf_wr[b], hin, b == 0 ? 1 : 0);
        // block output is back in hin for the next block (relu'd for b=0, raw for b=1)
    }
    k_pool<<<Nn / 16, 256, 0, stream>>>(hin, batch, gbuf);
    k_head<<<Ng / 4, 256, 0, stream>>>(gbuf, lin1_w, lin1_b, lin2_w, lin2_b, (float*)d_out);
}

// Round 7
// 505.807 us; speedup vs baseline: 1.5841x; 1.2085x over previous
//
#include <hip/hip_runtime.h>
#include <cstdint>
#include <cstddef>

#define Nn 50000
#define Ne 800000
#define Ng 1024
#define NFd 32
#define Rr 4
#define Hd 64
#define Od 16
#define MAXD 10
#define NSEG (Nn * Rr)
#define SCAN_BLK ((NSEG + 255) / 256)
#define ORDER_SZ (Nn + 48)                 // buckets padded to x4: max 11*3 pad
#define NB_MF ((ORDER_SZ + 15) / 16)       // block = 4 waves x 4 slots
#define NB_RG (Nn / 16)                    // block = 4 waves x 4 nodes

__device__ __forceinline__ float reluf(float v) { return v > 0.f ? v : 0.f; }
__device__ __forceinline__ int rfl(int v) { return __builtin_amdgcn_readfirstlane(v); }

// ---- per-edge relation argmax -> segment id (tgt*R+rel) + segment histogram ----
__global__ void k_rel_seg(const float4* __restrict__ ea, const int* __restrict__ eidx,
                          int* __restrict__ seg, int* __restrict__ cnt) {
    int e = blockIdx.x * 256 + threadIdx.x;
    if (e >= Ne) return;
    float4 a = ea[e];
    int bi = 0; float bv = a.x;
    if (a.y > bv) { bv = a.y; bi = 1; }
    if (a.z > bv) { bv = a.z; bi = 2; }
    if (a.w > bv) { bv = a.w; bi = 3; }
    int s = eidx[Ne + e] * Rr + bi;
    seg[e] = s;
    atomicAdd(&cnt[s], 1);
}

// ---- 3-kernel exclusive scan over cnt[NSEG] -> off[NSEG+1] ----
__global__ void k_scan1(const int* __restrict__ cnt, int* __restrict__ off,
                        int* __restrict__ bsum) {
    __shared__ int s[256];
    int t = threadIdx.x;
    int idx = blockIdx.x * 256 + t;
    int v = (idx < NSEG) ? cnt[idx] : 0;
    s[t] = v;
    __syncthreads();
    #pragma unroll
    for (int o = 1; o < 256; o <<= 1) {
        int x = (t >= o) ? s[t - o] : 0;
        __syncthreads();
        s[t] += x;
        __syncthreads();
    }
    if (idx < NSEG) off[idx] = s[t] - v;            // exclusive
    if (t == 255) bsum[blockIdx.x] = s[255];
}

__global__ void k_scan2(int* __restrict__ bsum) {
    __shared__ int s[1024];
    int t = threadIdx.x;
    int v = (t < SCAN_BLK) ? bsum[t] : 0;
    s[t] = v;
    __syncthreads();
    #pragma unroll
    for (int o = 1; o < 1024; o <<= 1) {
        int x = (t >= o) ? s[t - o] : 0;
        __syncthreads();
        s[t] += x;
        __syncthreads();
    }
    if (t < SCAN_BLK) bsum[t] = s[t] - v;           // exclusive block bases
}

__global__ void k_scan3(int* __restrict__ off, const int* __restrict__ bsum,
                        int* __restrict__ fill) {
    int idx = blockIdx.x * 256 + threadIdx.x;
    if (idx == 0) off[NSEG] = Ne;
    if (idx >= NSEG) return;
    int v = off[idx] + bsum[blockIdx.x];
    off[idx] = v;
    fill[idx] = v;
}

// ---- scatter edges into segment-sorted order (store src only) ----
__global__ void k_scatter(const int* __restrict__ eidx, const int* __restrict__ seg,
                          int* __restrict__ fill, int* __restrict__ sorted_src) {
    int e = blockIdx.x * 256 + threadIdx.x;
    if (e >= Ne) return;
    int pos = atomicAdd(&fill[seg[e]], 1);
    sorted_src[pos] = eidx[e];
}

// ---- embedding lookup: wave per node; writes relu'd row ----
__global__ void k_embed(const float* __restrict__ x, const float* __restrict__ emb,
                        float* __restrict__ h) {
    int wave = (blockIdx.x * 256 + threadIdx.x) >> 6;
    int lane = threadIdx.x & 63;
    if (wave >= Nn) return;
    float v = (lane < NFd) ? x[(size_t)wave * NFd + lane] : -1e30f;
    int idx = lane;
    #pragma unroll
    for (int off = 16; off >= 1; off >>= 1) {
        float ov = __shfl_down(v, off);
        int oi = __shfl_down(idx, off);
        if (ov > v || (ov == v && oi < idx)) { v = ov; idx = oi; }
    }
    idx = __shfl(idx, 0);
    h[(size_t)wave * Hd + lane] = reluf(emb[(size_t)idx * Hd + lane]);
}

// ---- degree bucketing from CSR offsets (LDS hist, 11 global atomics/block) ----
__global__ void k_bucket_count(const int* __restrict__ off, int* __restrict__ bcnt) {
    __shared__ int hist[16];
    if (threadIdx.x < 16) hist[threadIdx.x] = 0;
    __syncthreads();
    int n = blockIdx.x * 256 + threadIdx.x;
    if (n < Nn) {
        int d = min(off[n * Rr + Rr] - off[n * Rr], MAXD);
        atomicAdd(&hist[d], 1);
    }
    __syncthreads();
    if (threadIdx.x < 16) {
        int h = hist[threadIdx.x];
        if (h > 0) atomicAdd(&bcnt[threadIdx.x], h);
    }
}

__global__ void k_bucket_prefix(const int* __restrict__ bcnt, int* __restrict__ bbase) {
    if (threadIdx.x == 0 && blockIdx.x == 0) {
        int run = 0;
        for (int d = 0; d <= MAXD; d++) { bbase[d] = run; run += (bcnt[d] + 3) & ~3; }
    }
}

__global__ void k_bucket_scatter(const int* __restrict__ off, const int* __restrict__ bbase,
                                 int* __restrict__ bfill, int* __restrict__ order) {
    __shared__ int hist[16];
    __shared__ int base[16];
    if (threadIdx.x < 16) hist[threadIdx.x] = 0;
    __syncthreads();
    int n = blockIdx.x * 256 + threadIdx.x;
    int d = 0, rank = 0;
    bool valid = (n < Nn);
    if (valid) {
        d = min(off[n * Rr + Rr] - off[n * Rr], MAXD);
        rank = atomicAdd(&hist[d], 1);
    }
    __syncthreads();
    if (threadIdx.x < 16) {
        int h = hist[threadIdx.x];
        base[threadIdx.x] = (h > 0) ? atomicAdd(&bfill[threadIdx.x], h) : 0;
    }
    __syncthreads();
    if (valid) order[bbase[d] + base[d] + rank] = n | (d << 20);
}

// classify edge ee into relation via uniform boundaries, accumulate v
#define ACC4(v, ee)  {                                      \
    int rr = ((ee) >= e1) + ((ee) >= e2) + ((ee) >= e3);    \
    a0 += (rr == 0) ? (v) : 0.f;                            \
    a1 += (rr == 1) ? (v) : 0.f;                            \
    a2 += (rr == 2) ? (v) : 0.f;                            \
    a3 += (rr == 3) ? (v) : 0.f; }

// ---- FUSED RGCN layer: whole-range unrolled gather + transform ----
// Wave owns 4 nodes. A node's 4 relation segments are contiguous in ssrc
// (sorted by tgt*R+rel), so gather the full range with 8-wide unroll and
// classify per edge from uniform boundaries -> deep load queue (MLP).
__global__ __launch_bounds__(256) void k_rgcn_fused(
        const float* __restrict__ hin, const int* __restrict__ off,
        const int* __restrict__ ssrc, const float* __restrict__ W,
        const float* __restrict__ Wroot, const float* __restrict__ bias,
        float* __restrict__ hout) {
    __shared__ float lds[4][4][Rr][Hd];             // 16 KB: [wave][node][rel][k]
    int tid = threadIdx.x;
    int wv = tid >> 6, lane = tid & 63;
    int wave = rfl(blockIdx.x * 4 + wv);
    int n0 = wave * 4;
    // gather: per node, one unrolled pass over all 4 relation segments
    for (int i = 0; i < 4; i++) {
        int nb = (n0 + i) * Rr;
        int e0 = rfl(off[nb]);
        int e1 = rfl(off[nb + 1]);
        int e2 = rfl(off[nb + 2]);
        int e3 = rfl(off[nb + 3]);
        int e4 = rfl(off[nb + 4]);
        float a0 = 0.f, a1 = 0.f, a2 = 0.f, a3 = 0.f;
        int e = e0;
        for (; e + 8 <= e4; e += 8) {
            const int4 sA = *(const int4*)(ssrc + e);
            const int4 sB = *(const int4*)(ssrc + e + 4);
            float v0 = hin[(size_t)sA.x * Hd + lane];
            float v1 = hin[(size_t)sA.y * Hd + lane];
            float v2 = hin[(size_t)sA.z * Hd + lane];
            float v3 = hin[(size_t)sA.w * Hd + lane];
            float v4 = hin[(size_t)sB.x * Hd + lane];
            float v5 = hin[(size_t)sB.y * Hd + lane];
            float v6 = hin[(size_t)sB.z * Hd + lane];
            float v7 = hin[(size_t)sB.w * Hd + lane];
            ACC4(v0, e + 0); ACC4(v1, e + 1); ACC4(v2, e + 2); ACC4(v3, e + 3);
            ACC4(v4, e + 4); ACC4(v5, e + 5); ACC4(v6, e + 6); ACC4(v7, e + 7);
        }
        for (; e + 4 <= e4; e += 4) {
            const int4 sA = *(const int4*)(ssrc + e);
            float v0 = hin[(size_t)sA.x * Hd + lane];
            float v1 = hin[(size_t)sA.y * Hd + lane];
            float v2 = hin[(size_t)sA.z * Hd + lane];
            float v3 = hin[(size_t)sA.w * Hd + lane];
            ACC4(v0, e + 0); ACC4(v1, e + 1); ACC4(v2, e + 2); ACC4(v3, e + 3);
        }
        for (; e < e4; e++) {
            int s = rfl(ssrc[e]);
            float v = hin[(size_t)s * Hd + lane];
            ACC4(v, e);
        }
        lds[wv][i][0][lane] = a0 * ((e1 > e0) ? 1.f / (float)(e1 - e0) : 0.f);
        lds[wv][i][1][lane] = a1 * ((e2 > e1) ? 1.f / (float)(e2 - e1) : 0.f);
        lds[wv][i][2][lane] = a2 * ((e3 > e2) ? 1.f / (float)(e3 - e2) : 0.f);
        lds[wv][i][3][lane] = a3 * ((e4 > e3) ? 1.f / (float)(e4 - e3) : 0.f);
    }
    // transform
    float bj = bias[lane];
    float acc[4] = {bj, bj, bj, bj};
    const float* hb = hin + (size_t)n0 * Hd;        // root rows: broadcast reads
    for (int kc = 0; kc < Hd; kc += 4) {
        float w0 = Wroot[(kc + 0) * Hd + lane];
        float w1 = Wroot[(kc + 1) * Hd + lane];
        float w2 = Wroot[(kc + 2) * Hd + lane];
        float w3 = Wroot[(kc + 3) * Hd + lane];
        #pragma unroll
        for (int i = 0; i < 4; i++) {
            const float4 iv = *(const float4*)(hb + i * Hd + kc);
            acc[i] += iv.x * w0 + iv.y * w1 + iv.z * w2 + iv.w * w3;
        }
    }
    for (int r = 0; r < Rr; r++) {
        const float* Wp = W + (size_t)r * Hd * Hd;
        for (int kc = 0; kc < Hd; kc += 4) {
            float w0 = Wp[(kc + 0) * Hd + lane];
            float w1 = Wp[(kc + 1) * Hd + lane];
            float w2 = Wp[(kc + 2) * Hd + lane];
            float w3 = Wp[(kc + 3) * Hd + lane];
            #pragma unroll
            for (int i = 0; i < 4; i++) {
                const float4 iv = *(const float4*)(&lds[wv][i][r][kc]);
                acc[i] += iv.x * w0 + iv.y * w1 + iv.z * w2 + iv.w * w3;
            }
        }
    }
    #pragma unroll
    for (int i = 0; i < 4; i++) hout[(size_t)(n0 + i) * Hd + lane] = reluf(acc[i]);
}

// ---- FUSED MFConv layer: unrolled whole-range gather + degree-bucketed transform ----
// Wave owns 4 order-slots (buckets padded to x4 -> one shared degree d).
__global__ __launch_bounds__(256) void k_mf_fused(
        const float* __restrict__ hin, const int* __restrict__ off,
        const int* __restrict__ ssrc, const int* __restrict__ order,
        const float* __restrict__ Wl, const float* __restrict__ bl,
        const float* __restrict__ Wr, float* __restrict__ hout, int relu_out) {
    __shared__ float lds[4][4][Hd];                 // 4 KB: [wave][node][k]
    int tid = threadIdx.x;
    int wv = tid >> 6, lane = tid & 63;
    int slot0 = rfl(blockIdx.x * 16 + wv * 4);
    int ent[4];
    #pragma unroll
    for (int i = 0; i < 4; i++) ent[i] = rfl(order[slot0 + i]);
    int d = -1;
    #pragma unroll
    for (int i = 3; i >= 0; i--) if (ent[i] >= 0) d = ent[i] >> 20;
    if (d < 0) return;
    int n[4];
    #pragma unroll
    for (int i = 0; i < 4; i++) n[i] = (ent[i] >= 0) ? (ent[i] & 0xFFFFF) : 0;
    for (int i = 0; i < 4; i++) {
        int e0 = rfl(off[n[i] * Rr]);
        int e4 = rfl(off[n[i] * Rr + Rr]);
        float sA0 = 0.f, sA1 = 0.f;
        int e = e0;
        for (; e + 8 <= e4; e += 8) {
            const int4 sA = *(const int4*)(ssrc + e);
            const int4 sB = *(const int4*)(ssrc + e + 4);
            sA0 += hin[(size_t)sA.x * Hd + lane] + hin[(size_t)sA.y * Hd + lane]
                 + hin[(size_t)sA.z * Hd + lane] + hin[(size_t)sA.w * Hd + lane];
            sA1 += hin[(size_t)sB.x * Hd + lane] + hin[(size_t)sB.y * Hd + lane]
                 + hin[(size_t)sB.z * Hd + lane] + hin[(size_t)sB.w * Hd + lane];
        }
        for (; e + 4 <= e4; e += 4) {
            const int4 sA = *(const int4*)(ssrc + e);
            sA0 += hin[(size_t)sA.x * Hd + lane] + hin[(size_t)sA.y * Hd + lane]
                 + hin[(size_t)sA.z * Hd + lane] + hin[(size_t)sA.w * Hd + lane];
        }
        for (; e < e4; e++) {
            int s = rfl(ssrc[e]);
            sA0 += hin[(size_t)s * Hd + lane];
        }
        lds[wv][i][lane] = sA0 + sA1;
    }
    const float* wl = Wl + (size_t)d * Hd * Hd;
    const float* wr = Wr + (size_t)d * Hd * Hd;
    float acc[4] = {0.f, 0.f, 0.f, 0.f};
    for (int kc = 0; kc < Hd; kc += 4) {
        float a0 = wl[(kc + 0) * Hd + lane];
        float a1 = wl[(kc + 1) * Hd + lane];
        float a2 = wl[(kc + 2) * Hd + lane];
        float a3 = wl[(kc + 3) * Hd + lane];
        float b0 = wr[(kc + 0) * Hd + lane];
        float b1 = wr[(kc + 1) * Hd + lane];
        float b2 = wr[(kc + 2) * Hd + lane];
        float b3 = wr[(kc + 3) * Hd + lane];
        #pragma unroll
        for (int i = 0; i < 4; i++) {
            const float4 av = *(const float4*)(&lds[wv][i][kc]);
            const float4 hv = *(const float4*)(hin + (size_t)n[i] * Hd + kc);
            acc[i] += av.x * a0 + av.y * a1 + av.z * a2 + av.w * a3
                    + hv.x * b0 + hv.y * b1 + hv.z * b2 + hv.w * b3;
        }
    }
    float bb = bl[d * Hd + lane];
    #pragma unroll
    for (int i = 0; i < 4; i++)
        if (ent[i] >= 0) {
            float v = acc[i] + bb;
            hout[(size_t)n[i] * Hd + lane] = relu_out ? reluf(v) : v;
        }
}

// ---- global add pool (batch_idx is sorted -> mostly single fused atomic) ----
__global__ void k_pool(const float* __restrict__ h, const int* __restrict__ batch,
                       float* __restrict__ g) {
    int wave = rfl((blockIdx.x * 256 + threadIdx.x) >> 6);
    int lane = threadIdx.x & 63;
    int n0 = wave * 4;
    if (n0 >= Nn) return;
    int b0 = batch[n0], b1 = batch[n0 + 1], b2 = batch[n0 + 2], b3 = batch[n0 + 3];
    float v0 = h[(size_t)n0 * Hd + lane];
    float v1 = h[(size_t)(n0 + 1) * Hd + lane];
    float v2 = h[(size_t)(n0 + 2) * Hd + lane];
    float v3 = h[(size_t)(n0 + 3) * Hd + lane];
    if (b0 == b1 && b0 == b2 && b0 == b3) {
        unsafeAtomicAdd(&g[(size_t)b0 * Hd + lane], v0 + v1 + v2 + v3);
    } else {
        unsafeAtomicAdd(&g[(size_t)b0 * Hd + lane], v0);
        unsafeAtomicAdd(&g[(size_t)b1 * Hd + lane], v1);
        unsafeAtomicAdd(&g[(size_t)b2 * Hd + lane], v2);
        unsafeAtomicAdd(&g[(size_t)b3 * Hd + lane], v3);
    }
}

// ---- head: relu(g@lin1+b1)@lin2+b2, one wave per graph ----
__global__ void k_head(const float* __restrict__ g, const float* __restrict__ w1,
                       const float* __restrict__ b1, const float* __restrict__ w2,
                       const float* __restrict__ b2, float* __restrict__ out) {
    __shared__ float t[4][Hd];
    int wv = threadIdx.x >> 6;
    int lane = threadIdx.x & 63;
    int gi = blockIdx.x * 4 + wv;
    float acc = b1[lane];
    for (int k = 0; k < Hd; k++) acc += g[(size_t)gi * Hd + k] * w1[k * Hd + lane];
    t[wv][lane] = reluf(acc);
    __syncthreads();
    if (lane < Od) {
        float o = b2[lane];
        for (int k = 0; k < Hd; k++) o += t[wv][k] * w2[k * Od + lane];
        out[(size_t)gi * Od + lane] = o;
    }
}

extern "C" void kernel_launch(void* const* d_in, const int* in_sizes, int n_in,
                              void* d_out, int out_size, void* d_ws, size_t ws_size,
                              hipStream_t stream) {
    const float* x      = (const float*)d_in[0];
    const float* ea     = (const float*)d_in[1];
    const int*   eidx   = (const int*)d_in[2];
    const int*   batch  = (const int*)d_in[3];
    const float* emb    = (const float*)d_in[4];
    const float* lin1_w = (const float*)d_in[5];
    const float* lin1_b = (const float*)d_in[6];
    const float* lin2_w = (const float*)d_in[7];
    const float* lin2_b = (const float*)d_in[8];
    const float* rgcn_w[2]    = {(const float*)d_in[9],  (const float*)d_in[15]};
    const float* rgcn_root[2] = {(const float*)d_in[10], (const float*)d_in[16]};
    const float* rgcn_b[2]    = {(const float*)d_in[11], (const float*)d_in[17]};
    const float* mf_wl[2]     = {(const float*)d_in[12], (const float*)d_in[18]};
    const float* mf_bl[2]     = {(const float*)d_in[13], (const float*)d_in[19]};
    const float* mf_wr[2]     = {(const float*)d_in[14], (const float*)d_in[20]};

    char* p = (char*)d_ws;
    float* h0   = (float*)p; p += sizeof(float) * (size_t)Nn * Hd;
    float* h1   = (float*)p; p += sizeof(float) * (size_t)Nn * Hd;
    float* gbuf = (float*)p; p += sizeof(float) * (size_t)Ng * Hd;
    int* seg    = (int*)p;   p += sizeof(int) * (size_t)Ne;
    int* ssrc   = (int*)p;   p += sizeof(int) * (size_t)Ne;
    int* cnt    = (int*)p;   p += sizeof(int) * (size_t)NSEG;   // contiguous with bcnt/bfill
    int* bcnt   = (int*)p;   p += sizeof(int) * 16;
    int* bfill  = (int*)p;   p += sizeof(int) * 16;
    int* off    = (int*)p;   p += sizeof(int) * (size_t)(NSEG + 1);
    int* fill   = (int*)p;   p += sizeof(int) * (size_t)NSEG;
    int* bsum   = (int*)p;   p += sizeof(int) * 1024;
    int* bbase  = (int*)p;   p += sizeof(int) * 16;
    int* order  = (int*)p;   p += sizeof(int) * (size_t)ORDER_SZ;

    hipMemsetAsync(cnt, 0, sizeof(int) * ((size_t)NSEG + 32), stream);
    hipMemsetAsync(order, 0xFF, sizeof(int) * (size_t)ORDER_SZ, stream);
    hipMemsetAsync(gbuf, 0, sizeof(float) * (size_t)Ng * Hd, stream);

    k_rel_seg<<<Ne / 256, 256, 0, stream>>>((const float4*)ea, eidx, seg, cnt);
    k_scan1<<<SCAN_BLK, 256, 0, stream>>>(cnt, off, bsum);
    k_scan2<<<1, 1024, 0, stream>>>(bsum);
    k_scan3<<<SCAN_BLK, 256, 0, stream>>>(off, bsum, fill);
    k_scatter<<<Ne / 256, 256, 0, stream>>>(eidx, seg, fill, ssrc);
    k_embed<<<Nn / 4, 256, 0, stream>>>(x, emb, h0);
    k_bucket_count<<<(Nn + 255) / 256, 256, 0, stream>>>(off, bcnt);
    k_bucket_prefix<<<1, 64, 0, stream>>>(bcnt, bbase);
    k_bucket_scatter<<<(Nn + 255) / 256, 256, 0, stream>>>(off, bbase, bfill, order);

    float* hin = h0;
    float* hout = h1;
    for (int b = 0; b < 2; b++) {
        k_rgcn_fused<<<NB_RG, 256, 0, stream>>>(hin, off, ssrc, rgcn_w[b], rgcn_root[b],
                                                rgcn_b[b], hout);
        k_mf_fused<<<NB_MF, 256, 0, stream>>>(hout, off, ssrc, order, mf_wl[b],
                                              mf_bl[b], mf_wr[b], hin, b == 0 ? 1 : 0);
        // block output is back in hin for the next block (relu'd for b=0, raw for b=1)
    }
    k_pool<<<Nn / 16, 256, 0, stream>>>(hin, batch, gbuf);
    k_head<<<Ng / 4, 256, 0, stream>>>(gbuf, lin1_w, lin1_b, lin2_w, lin2_b, (float*)d_out);
}

// Round 8
// 502.697 us; speedup vs baseline: 1.5939x; 1.0062x over previous
//
#include <hip/hip_runtime.h>
#include <cstdint>
#include <cstddef>

#define Nn 50000
#define Ne 800000
#define Ng 1024
#define NFd 32
#define Rr 4
#define Hd 64
#define Od 16
#define MAXD 10
#define NSEG (Nn * Rr)
#define SCAN_BLK ((NSEG + 255) / 256)
#define ORDER_SZ (Nn + 48)                 // buckets padded to x4: max 11*3 pad
#define NB_MF ((ORDER_SZ + 15) / 16)       // block = 4 waves x 4 slots
#define NB_RG (Nn / 16)                    // block = 4 waves x 4 nodes

__device__ __forceinline__ float reluf(float v) { return v > 0.f ? v : 0.f; }
__device__ __forceinline__ int rfl(int v) { return __builtin_amdgcn_readfirstlane(v); }

// ---- per-edge relation argmax -> segment id (tgt*R+rel) + segment histogram ----
__global__ void k_rel_seg(const float4* __restrict__ ea, const int* __restrict__ eidx,
                          int* __restrict__ seg, int* __restrict__ cnt) {
    int e = blockIdx.x * 256 + threadIdx.x;
    if (e >= Ne) return;
    float4 a = ea[e];
    int bi = 0; float bv = a.x;
    if (a.y > bv) { bv = a.y; bi = 1; }
    if (a.z > bv) { bv = a.z; bi = 2; }
    if (a.w > bv) { bv = a.w; bi = 3; }
    int s = eidx[Ne + e] * Rr + bi;
    seg[e] = s;
    atomicAdd(&cnt[s], 1);
}

// ---- 3-kernel exclusive scan over cnt[NSEG] -> off[NSEG+1] ----
__global__ void k_scan1(const int* __restrict__ cnt, int* __restrict__ off,
                        int* __restrict__ bsum) {
    __shared__ int s[256];
    int t = threadIdx.x;
    int idx = blockIdx.x * 256 + t;
    int v = (idx < NSEG) ? cnt[idx] : 0;
    s[t] = v;
    __syncthreads();
    #pragma unroll
    for (int o = 1; o < 256; o <<= 1) {
        int x = (t >= o) ? s[t - o] : 0;
        __syncthreads();
        s[t] += x;
        __syncthreads();
    }
    if (idx < NSEG) off[idx] = s[t] - v;            // exclusive
    if (t == 255) bsum[blockIdx.x] = s[255];
}

__global__ void k_scan2(int* __restrict__ bsum) {
    __shared__ int s[1024];
    int t = threadIdx.x;
    int v = (t < SCAN_BLK) ? bsum[t] : 0;
    s[t] = v;
    __syncthreads();
    #pragma unroll
    for (int o = 1; o < 1024; o <<= 1) {
        int x = (t >= o) ? s[t - o] : 0;
        __syncthreads();
        s[t] += x;
        __syncthreads();
    }
    if (t < SCAN_BLK) bsum[t] = s[t] - v;           // exclusive block bases
}

__global__ void k_scan3(int* __restrict__ off, const int* __restrict__ bsum,
                        int* __restrict__ fill) {
    int idx = blockIdx.x * 256 + threadIdx.x;
    if (idx == 0) off[NSEG] = Ne;
    if (idx >= NSEG) return;
    int v = off[idx] + bsum[blockIdx.x];
    off[idx] = v;
    fill[idx] = v;
}

// ---- scatter edges into segment-sorted order (store src only) ----
__global__ void k_scatter(const int* __restrict__ eidx, const int* __restrict__ seg,
                          int* __restrict__ fill, int* __restrict__ sorted_src) {
    int e = blockIdx.x * 256 + threadIdx.x;
    if (e >= Ne) return;
    int pos = atomicAdd(&fill[seg[e]], 1);
    sorted_src[pos] = eidx[e];
}

// ---- embedding lookup: wave per node; writes relu'd row ----
__global__ void k_embed(const float* __restrict__ x, const float* __restrict__ emb,
                        float* __restrict__ h) {
    int wave = (blockIdx.x * 256 + threadIdx.x) >> 6;
    int lane = threadIdx.x & 63;
    if (wave >= Nn) return;
    float v = (lane < NFd) ? x[(size_t)wave * NFd + lane] : -1e30f;
    int idx = lane;
    #pragma unroll
    for (int off = 16; off >= 1; off >>= 1) {
        float ov = __shfl_down(v, off);
        int oi = __shfl_down(idx, off);
        if (ov > v || (ov == v && oi < idx)) { v = ov; idx = oi; }
    }
    idx = __shfl(idx, 0);
    h[(size_t)wave * Hd + lane] = reluf(emb[(size_t)idx * Hd + lane]);
}

// ---- degree bucketing from CSR offsets (LDS hist, 11 global atomics/block) ----
__global__ void k_bucket_count(const int* __restrict__ off, int* __restrict__ bcnt) {
    __shared__ int hist[16];
    if (threadIdx.x < 16) hist[threadIdx.x] = 0;
    __syncthreads();
    int n = blockIdx.x * 256 + threadIdx.x;
    if (n < Nn) {
        int d = min(off[n * Rr + Rr] - off[n * Rr], MAXD);
        atomicAdd(&hist[d], 1);
    }
    __syncthreads();
    if (threadIdx.x < 16) {
        int h = hist[threadIdx.x];
        if (h > 0) atomicAdd(&bcnt[threadIdx.x], h);
    }
}

__global__ void k_bucket_prefix(const int* __restrict__ bcnt, int* __restrict__ bbase) {
    if (threadIdx.x == 0 && blockIdx.x == 0) {
        int run = 0;
        for (int d = 0; d <= MAXD; d++) { bbase[d] = run; run += (bcnt[d] + 3) & ~3; }
    }
}

__global__ void k_bucket_scatter(const int* __restrict__ off, const int* __restrict__ bbase,
                                 int* __restrict__ bfill, int* __restrict__ order) {
    __shared__ int hist[16];
    __shared__ int base[16];
    if (threadIdx.x < 16) hist[threadIdx.x] = 0;
    __syncthreads();
    int n = blockIdx.x * 256 + threadIdx.x;
    int d = 0, rank = 0;
    bool valid = (n < Nn);
    if (valid) {
        d = min(off[n * Rr + Rr] - off[n * Rr], MAXD);
        rank = atomicAdd(&hist[d], 1);
    }
    __syncthreads();
    if (threadIdx.x < 16) {
        int h = hist[threadIdx.x];
        base[threadIdx.x] = (h > 0) ? atomicAdd(&bfill[threadIdx.x], h) : 0;
    }
    __syncthreads();
    if (valid) order[bbase[d] + base[d] + rank] = n | (d << 20);
}

// classify edge ee via wave-uniform boundaries -> 4 uniform scalar scales
// (SALU: compares + cselect), then 4 v_fmac with SGPR multiplicand.
#define ACCS(v, ee)  {                                      \
    int rr = ((ee) >= e1) + ((ee) >= e2) + ((ee) >= e3);    \
    float s0 = (rr == 0) ? i0 : 0.f;                        \
    float s1 = (rr == 1) ? i1 : 0.f;                        \
    float s2 = (rr == 2) ? i2 : 0.f;                        \
    float s3 = (rr == 3) ? i3 : 0.f;                        \
    a0 = fmaf(s0, (v), a0);                                 \
    a1 = fmaf(s1, (v), a1);                                 \
    a2 = fmaf(s2, (v), a2);                                 \
    a3 = fmaf(s3, (v), a3); }

// ---- FUSED RGCN layer: 16-deep unrolled gather + transform ----
__global__ __launch_bounds__(256) void k_rgcn_fused(
        const float* __restrict__ hin, const int* __restrict__ off,
        const int* __restrict__ ssrc, const float* __restrict__ W,
        const float* __restrict__ Wroot, const float* __restrict__ bias,
        float* __restrict__ hout) {
    __shared__ float lds[4][4][Rr][Hd];             // 16 KB: [wave][node][rel][k]
    int tid = threadIdx.x;
    int wv = tid >> 6, lane = tid & 63;
    int wave = rfl(blockIdx.x * 4 + wv);
    int n0 = wave * 4;
    // gather: per node, one pass over its contiguous 4-relation edge range
    for (int i = 0; i < 4; i++) {
        int nb = (n0 + i) * Rr;
        int e0 = rfl(off[nb]);
        int e1 = rfl(off[nb + 1]);
        int e2 = rfl(off[nb + 2]);
        int e3 = rfl(off[nb + 3]);
        int e4 = rfl(off[nb + 4]);
        float i0 = (e1 > e0) ? 1.f / (float)(e1 - e0) : 0.f;
        float i1 = (e2 > e1) ? 1.f / (float)(e2 - e1) : 0.f;
        float i2 = (e3 > e2) ? 1.f / (float)(e3 - e2) : 0.f;
        float i3 = (e4 > e3) ? 1.f / (float)(e4 - e3) : 0.f;
        float a0 = 0.f, a1 = 0.f, a2 = 0.f, a3 = 0.f;
        int e = e0;
        for (; e + 16 <= e4; e += 16) {             // 16 loads in flight
            const int4 sA = *(const int4*)(ssrc + e);
            const int4 sB = *(const int4*)(ssrc + e + 4);
            const int4 sC = *(const int4*)(ssrc + e + 8);
            const int4 sD = *(const int4*)(ssrc + e + 12);
            float v0 = hin[(size_t)sA.x * Hd + lane];
            float v1 = hin[(size_t)sA.y * Hd + lane];
            float v2 = hin[(size_t)sA.z * Hd + lane];
            float v3 = hin[(size_t)sA.w * Hd + lane];
            float v4 = hin[(size_t)sB.x * Hd + lane];
            float v5 = hin[(size_t)sB.y * Hd + lane];
            float v6 = hin[(size_t)sB.z * Hd + lane];
            float v7 = hin[(size_t)sB.w * Hd + lane];
            float v8 = hin[(size_t)sC.x * Hd + lane];
            float v9 = hin[(size_t)sC.y * Hd + lane];
            float vA = hin[(size_t)sC.z * Hd + lane];
            float vB = hin[(size_t)sC.w * Hd + lane];
            float vC = hin[(size_t)sD.x * Hd + lane];
            float vD = hin[(size_t)sD.y * Hd + lane];
            float vE = hin[(size_t)sD.z * Hd + lane];
            float vF = hin[(size_t)sD.w * Hd + lane];
            ACCS(v0, e + 0);  ACCS(v1, e + 1);  ACCS(v2, e + 2);  ACCS(v3, e + 3);
            ACCS(v4, e + 4);  ACCS(v5, e + 5);  ACCS(v6, e + 6);  ACCS(v7, e + 7);
            ACCS(v8, e + 8);  ACCS(v9, e + 9);  ACCS(vA, e + 10); ACCS(vB, e + 11);
            ACCS(vC, e + 12); ACCS(vD, e + 13); ACCS(vE, e + 14); ACCS(vF, e + 15);
        }
        for (; e + 4 <= e4; e += 4) {
            const int4 sA = *(const int4*)(ssrc + e);
            float v0 = hin[(size_t)sA.x * Hd + lane];
            float v1 = hin[(size_t)sA.y * Hd + lane];
            float v2 = hin[(size_t)sA.z * Hd + lane];
            float v3 = hin[(size_t)sA.w * Hd + lane];
            ACCS(v0, e + 0); ACCS(v1, e + 1); ACCS(v2, e + 2); ACCS(v3, e + 3);
        }
        for (; e < e4; e++) {
            int s = rfl(ssrc[e]);
            float v = hin[(size_t)s * Hd + lane];
            ACCS(v, e);
        }
        lds[wv][i][0][lane] = a0;                   // means (inv folded into scales)
        lds[wv][i][1][lane] = a1;
        lds[wv][i][2][lane] = a2;
        lds[wv][i][3][lane] = a3;
    }
    // transform
    float bj = bias[lane];
    float acc[4] = {bj, bj, bj, bj};
    const float* hb = hin + (size_t)n0 * Hd;        // root rows: broadcast reads
    for (int kc = 0; kc < Hd; kc += 4) {
        float w0 = Wroot[(kc + 0) * Hd + lane];
        float w1 = Wroot[(kc + 1) * Hd + lane];
        float w2 = Wroot[(kc + 2) * Hd + lane];
        float w3 = Wroot[(kc + 3) * Hd + lane];
        #pragma unroll
        for (int i = 0; i < 4; i++) {
            const float4 iv = *(const float4*)(hb + i * Hd + kc);
            acc[i] += iv.x * w0 + iv.y * w1 + iv.z * w2 + iv.w * w3;
        }
    }
    for (int r = 0; r < Rr; r++) {
        const float* Wp = W + (size_t)r * Hd * Hd;
        for (int kc = 0; kc < Hd; kc += 4) {
            float w0 = Wp[(kc + 0) * Hd + lane];
            float w1 = Wp[(kc + 1) * Hd + lane];
            float w2 = Wp[(kc + 2) * Hd + lane];
            float w3 = Wp[(kc + 3) * Hd + lane];
            #pragma unroll
            for (int i = 0; i < 4; i++) {
                const float4 iv = *(const float4*)(&lds[wv][i][r][kc]);
                acc[i] += iv.x * w0 + iv.y * w1 + iv.z * w2 + iv.w * w3;
            }
        }
    }
    #pragma unroll
    for (int i = 0; i < 4; i++) hout[(size_t)(n0 + i) * Hd + lane] = reluf(acc[i]);
}

// ---- FUSED MFConv layer: 16-deep unrolled gather + degree-bucketed transform ----
__global__ __launch_bounds__(256) void k_mf_fused(
        const float* __restrict__ hin, const int* __restrict__ off,
        const int* __restrict__ ssrc, const int* __restrict__ order,
        const float* __restrict__ Wl, const float* __restrict__ bl,
        const float* __restrict__ Wr, float* __restrict__ hout, int relu_out) {
    __shared__ float lds[4][4][Hd];                 // 4 KB: [wave][node][k]
    int tid = threadIdx.x;
    int wv = tid >> 6, lane = tid & 63;
    int slot0 = rfl(blockIdx.x * 16 + wv * 4);
    int ent[4];
    #pragma unroll
    for (int i = 0; i < 4; i++) ent[i] = rfl(order[slot0 + i]);
    int d = -1;
    #pragma unroll
    for (int i = 3; i >= 0; i--) if (ent[i] >= 0) d = ent[i] >> 20;
    if (d < 0) return;
    int n[4];
    #pragma unroll
    for (int i = 0; i < 4; i++) n[i] = (ent[i] >= 0) ? (ent[i] & 0xFFFFF) : 0;
    for (int i = 0; i < 4; i++) {
        int e0 = rfl(off[n[i] * Rr]);
        int e4 = rfl(off[n[i] * Rr + Rr]);
        float p0 = 0.f, p1 = 0.f, p2 = 0.f, p3 = 0.f;
        int e = e0;
        for (; e + 16 <= e4; e += 16) {
            const int4 sA = *(const int4*)(ssrc + e);
            const int4 sB = *(const int4*)(ssrc + e + 4);
            const int4 sC = *(const int4*)(ssrc + e + 8);
            const int4 sD = *(const int4*)(ssrc + e + 12);
            p0 += hin[(size_t)sA.x * Hd + lane] + hin[(size_t)sA.y * Hd + lane]
                + hin[(size_t)sA.z * Hd + lane] + hin[(size_t)sA.w * Hd + lane];
            p1 += hin[(size_t)sB.x * Hd + lane] + hin[(size_t)sB.y * Hd + lane]
                + hin[(size_t)sB.z * Hd + lane] + hin[(size_t)sB.w * Hd + lane];
            p2 += hin[(size_t)sC.x * Hd + lane] + hin[(size_t)sC.y * Hd + lane]
                + hin[(size_t)sC.z * Hd + lane] + hin[(size_t)sC.w * Hd + lane];
            p3 += hin[(size_t)sD.x * Hd + lane] + hin[(size_t)sD.y * Hd + lane]
                + hin[(size_t)sD.z * Hd + lane] + hin[(size_t)sD.w * Hd + lane];
        }
        for (; e + 4 <= e4; e += 4) {
            const int4 sA = *(const int4*)(ssrc + e);
            p0 += hin[(size_t)sA.x * Hd + lane] + hin[(size_t)sA.y * Hd + lane]
                + hin[(size_t)sA.z * Hd + lane] + hin[(size_t)sA.w * Hd + lane];
        }
        for (; e < e4; e++) {
            int s = rfl(ssrc[e]);
            p0 += hin[(size_t)s * Hd + lane];
        }
        lds[wv][i][lane] = (p0 + p1) + (p2 + p3);
    }
    const float* wl = Wl + (size_t)d * Hd * Hd;
    const float* wr = Wr + (size_t)d * Hd * Hd;
    float acc[4] = {0.f, 0.f, 0.f, 0.f};
    for (int kc = 0; kc < Hd; kc += 4) {
        float a0 = wl[(kc + 0) * Hd + lane];
        float a1 = wl[(kc + 1) * Hd + lane];
        float a2 = wl[(kc + 2) * Hd + lane];
        float a3 = wl[(kc + 3) * Hd + lane];
        float b0 = wr[(kc + 0) * Hd + lane];
        float b1 = wr[(kc + 1) * Hd + lane];
        float b2 = wr[(kc + 2) * Hd + lane];
        float b3 = wr[(kc + 3) * Hd + lane];
        #pragma unroll
        for (int i = 0; i < 4; i++) {
            const float4 av = *(const float4*)(&lds[wv][i][kc]);
            const float4 hv = *(const float4*)(hin + (size_t)n[i] * Hd + kc);
            acc[i] += av.x * a0 + av.y * a1 + av.z * a2 + av.w * a3
                    + hv.x * b0 + hv.y * b1 + hv.z * b2 + hv.w * b3;
        }
    }
    float bb = bl[d * Hd + lane];
    #pragma unroll
    for (int i = 0; i < 4; i++)
        if (ent[i] >= 0) {
            float v = acc[i] + bb;
            hout[(size_t)n[i] * Hd + lane] = relu_out ? reluf(v) : v;
        }
}

// ---- global add pool (batch_idx is sorted -> mostly single fused atomic) ----
__global__ void k_pool(const float* __restrict__ h, const int* __restrict__ batch,
                       float* __restrict__ g) {
    int wave = rfl((blockIdx.x * 256 + threadIdx.x) >> 6);
    int lane = threadIdx.x & 63;
    int n0 = wave * 4;
    if (n0 >= Nn) return;
    int b0 = batch[n0], b1 = batch[n0 + 1], b2 = batch[n0 + 2], b3 = batch[n0 + 3];
    float v0 = h[(size_t)n0 * Hd + lane];
    float v1 = h[(size_t)(n0 + 1) * Hd + lane];
    float v2 = h[(size_t)(n0 + 2) * Hd + lane];
    float v3 = h[(size_t)(n0 + 3) * Hd + lane];
    if (b0 == b1 && b0 == b2 && b0 == b3) {
        unsafeAtomicAdd(&g[(size_t)b0 * Hd + lane], v0 + v1 + v2 + v3);
    } else {
        unsafeAtomicAdd(&g[(size_t)b0 * Hd + lane], v0);
        unsafeAtomicAdd(&g[(size_t)b1 * Hd + lane], v1);
        unsafeAtomicAdd(&g[(size_t)b2 * Hd + lane], v2);
        unsafeAtomicAdd(&g[(size_t)b3 * Hd + lane], v3);
    }
}

// ---- head: relu(g@lin1+b1)@lin2+b2, one wave per graph ----
__global__ void k_head(const float* __restrict__ g, const float* __restrict__ w1,
                       const float* __restrict__ b1, const float* __restrict__ w2,
                       const float* __restrict__ b2, float* __restrict__ out) {
    __shared__ float t[4][Hd];
    int wv = threadIdx.x >> 6;
    int lane = threadIdx.x & 63;
    int gi = blockIdx.x * 4 + wv;
    float acc = b1[lane];
    for (int k = 0; k < Hd; k++) acc += g[(size_t)gi * Hd + k] * w1[k * Hd + lane];
    t[wv][lane] = reluf(acc);
    __syncthreads();
    if (lane < Od) {
        float o = b2[lane];
        for (int k = 0; k < Hd; k++) o += t[wv][k] * w2[k * Od + lane];
        out[(size_t)gi * Od + lane] = o;
    }
}

extern "C" void kernel_launch(void* const* d_in, const int* in_sizes, int n_in,
                              void* d_out, int out_size, void* d_ws, size_t ws_size,
                              hipStream_t stream) {
    const float* x      = (const float*)d_in[0];
    const float* ea     = (const float*)d_in[1];
    const int*   eidx   = (const int*)d_in[2];
    const int*   batch  = (const int*)d_in[3];
    const float* emb    = (const float*)d_in[4];
    const float* lin1_w = (const float*)d_in[5];
    const float* lin1_b = (const float*)d_in[6];
    const float* lin2_w = (const float*)d_in[7];
    const float* lin2_b = (const float*)d_in[8];
    const float* rgcn_w[2]    = {(const float*)d_in[9],  (const float*)d_in[15]};
    const float* rgcn_root[2] = {(const float*)d_in[10], (const float*)d_in[16]};
    const float* rgcn_b[2]    = {(const float*)d_in[11], (const float*)d_in[17]};
    const float* mf_wl[2]     = {(const float*)d_in[12], (const float*)d_in[18]};
    const float* mf_bl[2]     = {(const float*)d_in[13], (const float*)d_in[19]};
    const float* mf_wr[2]     = {(const float*)d_in[14], (const float*)d_in[20]};

    char* p = (char*)d_ws;
    float* h0   = (float*)p; p += sizeof(float) * (size_t)Nn * Hd;
    float* h1   = (float*)p; p += sizeof(float) * (size_t)Nn * Hd;
    float* gbuf = (float*)p; p += sizeof(float) * (size_t)Ng * Hd;
    int* seg    = (int*)p;   p += sizeof(int) * (size_t)Ne;
    int* ssrc   = (int*)p;   p += sizeof(int) * (size_t)Ne;
    int* cnt    = (int*)p;   p += sizeof(int) * (size_t)NSEG;   // contiguous with bcnt/bfill
    int* bcnt   = (int*)p;   p += sizeof(int) * 16;
    int* bfill  = (int*)p;   p += sizeof(int) * 16;
    int* off    = (int*)p;   p += sizeof(int) * (size_t)(NSEG + 1);
    int* fill   = (int*)p;   p += sizeof(int) * (size_t)NSEG;
    int* bsum   = (int*)p;   p += sizeof(int) * 1024;
    int* bbase  = (int*)p;   p += sizeof(int) * 16;
    int* order  = (int*)p;   p += sizeof(int) * (size_t)ORDER_SZ;

    hipMemsetAsync(cnt, 0, sizeof(int) * ((size_t)NSEG + 32), stream);
    hipMemsetAsync(order, 0xFF, sizeof(int) * (size_t)ORDER_SZ, stream);
    hipMemsetAsync(gbuf, 0, sizeof(float) * (size_t)Ng * Hd, stream);

    k_rel_seg<<<Ne / 256, 256, 0, stream>>>((const float4*)ea, eidx, seg, cnt);
    k_scan1<<<SCAN_BLK, 256, 0, stream>>>(cnt, off, bsum);
    k_scan2<<<1, 1024, 0, stream>>>(bsum);
    k_scan3<<<SCAN_BLK, 256, 0, stream>>>(off, bsum, fill);
    k_scatter<<<Ne / 256, 256, 0, stream>>>(eidx, seg, fill, ssrc);
    k_embed<<<Nn / 4, 256, 0, stream>>>(x, emb, h0);
    k_bucket_count<<<(Nn + 255) / 256, 256, 0, stream>>>(off, bcnt);
    k_bucket_prefix<<<1, 64, 0, stream>>>(bcnt, bbase);
    k_bucket_scatter<<<(Nn + 255) / 256, 256, 0, stream>>>(off, bbase, bfill, order);

    float* hin = h0;
    float* hout = h1;
    for (int b = 0; b < 2; b++) {
        k_rgcn_fused<<<NB_RG, 256, 0, stream>>>(hin, off, ssrc, rgcn_w[b], rgcn_root[b],
                                                rgcn_b[b], hout);
        k_mf_fused<<<NB_MF, 256, 0, stream>>>(hout, off, ssrc, order, mf_wl[b],
                                              mf_bl[b], mf_wr[b], hin, b == 0 ? 1 : 0);
        // block output is back in hin for the next block (relu'd for b=0, raw for b=1)
    }
    k_pool<<<Nn / 16, 256, 0, stream>>>(hin, batch, gbuf);
    k_head<<<Ng / 4, 256, 0, stream>>>(gbuf, lin1_w, lin1_b, lin2_w, lin2_b, (float*)d_out);
}

// Round 9
// 481.591 us; speedup vs baseline: 1.6638x; 1.0438x over previous
//
#include <hip/hip_runtime.h>
#include <cstdint>
#include <cstddef>

#define Nn 50000
#define Ne 800000
#define Ng 1024
#define NFd 32
#define Rr 4
#define Hd 64
#define Od 16
#define MAXD 10
#define NSEG (Nn * Rr)
#define SCAN_BLK ((NSEG + 255) / 256)
#define ORDER_SZ (Nn + 48)                 // buckets padded to x4: max 11*3 pad
#define NB_MF ((ORDER_SZ + 15) / 16)       // block = 4 waves x 4 slots
#define NB_RG (Nn / 16)                    // block = 4 waves x 4 nodes
#define NB_GEMM ((Nn + 63) / 64)           // 782 blocks of 64 nodes
#define LDA 68                             // padded A leading dim (bank-conflict-free)

__device__ __forceinline__ float reluf(float v) { return v > 0.f ? v : 0.f; }
__device__ __forceinline__ int rfl(int v) { return __builtin_amdgcn_readfirstlane(v); }

// ---- per-edge relation argmax -> segment id (tgt*R+rel) + segment histogram ----
__global__ void k_rel_seg(const float4* __restrict__ ea, const int* __restrict__ eidx,
                          int* __restrict__ seg, int* __restrict__ cnt) {
    int e = blockIdx.x * 256 + threadIdx.x;
    if (e >= Ne) return;
    float4 a = ea[e];
    int bi = 0; float bv = a.x;
    if (a.y > bv) { bv = a.y; bi = 1; }
    if (a.z > bv) { bv = a.z; bi = 2; }
    if (a.w > bv) { bv = a.w; bi = 3; }
    int s = eidx[Ne + e] * Rr + bi;
    seg[e] = s;
    atomicAdd(&cnt[s], 1);
}

// ---- 3-kernel exclusive scan over cnt[NSEG] -> off[NSEG+1] ----
__global__ void k_scan1(const int* __restrict__ cnt, int* __restrict__ off,
                        int* __restrict__ bsum) {
    __shared__ int s[256];
    int t = threadIdx.x;
    int idx = blockIdx.x * 256 + t;
    int v = (idx < NSEG) ? cnt[idx] : 0;
    s[t] = v;
    __syncthreads();
    #pragma unroll
    for (int o = 1; o < 256; o <<= 1) {
        int x = (t >= o) ? s[t - o] : 0;
        __syncthreads();
        s[t] += x;
        __syncthreads();
    }
    if (idx < NSEG) off[idx] = s[t] - v;            // exclusive
    if (t == 255) bsum[blockIdx.x] = s[255];
}

__global__ void k_scan2(int* __restrict__ bsum) {
    __shared__ int s[1024];
    int t = threadIdx.x;
    int v = (t < SCAN_BLK) ? bsum[t] : 0;
    s[t] = v;
    __syncthreads();
    #pragma unroll
    for (int o = 1; o < 1024; o <<= 1) {
        int x = (t >= o) ? s[t - o] : 0;
        __syncthreads();
        s[t] += x;
        __syncthreads();
    }
    if (t < SCAN_BLK) bsum[t] = s[t] - v;           // exclusive block bases
}

__global__ void k_scan3(int* __restrict__ off, const int* __restrict__ bsum,
                        int* __restrict__ fill) {
    int idx = blockIdx.x * 256 + threadIdx.x;
    if (idx == 0) off[NSEG] = Ne;
    if (idx >= NSEG) return;
    int v = off[idx] + bsum[blockIdx.x];
    off[idx] = v;
    fill[idx] = v;
}

// ---- scatter edges into segment-sorted order (store src only) ----
__global__ void k_scatter(const int* __restrict__ eidx, const int* __restrict__ seg,
                          int* __restrict__ fill, int* __restrict__ sorted_src) {
    int e = blockIdx.x * 256 + threadIdx.x;
    if (e >= Ne) return;
    int pos = atomicAdd(&fill[seg[e]], 1);
    sorted_src[pos] = eidx[e];
}

// ---- embedding lookup: wave per node; writes relu'd row ----
__global__ void k_embed(const float* __restrict__ x, const float* __restrict__ emb,
                        float* __restrict__ h) {
    int wave = (blockIdx.x * 256 + threadIdx.x) >> 6;
    int lane = threadIdx.x & 63;
    if (wave >= Nn) return;
    float v = (lane < NFd) ? x[(size_t)wave * NFd + lane] : -1e30f;
    int idx = lane;
    #pragma unroll
    for (int off = 16; off >= 1; off >>= 1) {
        float ov = __shfl_down(v, off);
        int oi = __shfl_down(idx, off);
        if (ov > v || (ov == v && oi < idx)) { v = ov; idx = oi; }
    }
    idx = __shfl(idx, 0);
    h[(size_t)wave * Hd + lane] = reluf(emb[(size_t)idx * Hd + lane]);
}

// ---- degree bucketing from CSR offsets (LDS hist, 11 global atomics/block) ----
__global__ void k_bucket_count(const int* __restrict__ off, int* __restrict__ bcnt) {
    __shared__ int hist[16];
    if (threadIdx.x < 16) hist[threadIdx.x] = 0;
    __syncthreads();
    int n = blockIdx.x * 256 + threadIdx.x;
    if (n < Nn) {
        int d = min(off[n * Rr + Rr] - off[n * Rr], MAXD);
        atomicAdd(&hist[d], 1);
    }
    __syncthreads();
    if (threadIdx.x < 16) {
        int h = hist[threadIdx.x];
        if (h > 0) atomicAdd(&bcnt[threadIdx.x], h);
    }
}

__global__ void k_bucket_prefix(const int* __restrict__ bcnt, int* __restrict__ bbase) {
    if (threadIdx.x == 0 && blockIdx.x == 0) {
        int run = 0;
        for (int d = 0; d <= MAXD; d++) { bbase[d] = run; run += (bcnt[d] + 3) & ~3; }
    }
}

__global__ void k_bucket_scatter(const int* __restrict__ off, const int* __restrict__ bbase,
                                 int* __restrict__ bfill, int* __restrict__ order) {
    __shared__ int hist[16];
    __shared__ int base[16];
    if (threadIdx.x < 16) hist[threadIdx.x] = 0;
    __syncthreads();
    int n = blockIdx.x * 256 + threadIdx.x;
    int d = 0, rank = 0;
    bool valid = (n < Nn);
    if (valid) {
        d = min(off[n * Rr + Rr] - off[n * Rr], MAXD);
        rank = atomicAdd(&hist[d], 1);
    }
    __syncthreads();
    if (threadIdx.x < 16) {
        int h = hist[threadIdx.x];
        base[threadIdx.x] = (h > 0) ? atomicAdd(&bfill[threadIdx.x], h) : 0;
    }
    __syncthreads();
    if (valid) order[bbase[d] + base[d] + rank] = n | (d << 20);
}

// classify edge ee via wave-uniform boundaries -> 4 uniform scalar scales
#define ACCS(v, ee)  {                                      \
    int rr = ((ee) >= e1) + ((ee) >= e2) + ((ee) >= e3);    \
    float s0 = (rr == 0) ? i0 : 0.f;                        \
    float s1 = (rr == 1) ? i1 : 0.f;                        \
    float s2 = (rr == 2) ? i2 : 0.f;                        \
    float s3 = (rr == 3) ? i3 : 0.f;                        \
    a0 = fmaf(s0, (v), a0);                                 \
    a1 = fmaf(s1, (v), a1);                                 \
    a2 = fmaf(s2, (v), a2);                                 \
    a3 = fmaf(s3, (v), a3); }

// ---- RGCN gather: 16-deep unrolled gather -> rel-major means aggR[r][n][64] ----
__global__ __launch_bounds__(256) void k_rgcn_gather(
        const float* __restrict__ hin, const int* __restrict__ off,
        const int* __restrict__ ssrc, float* __restrict__ aggR) {
    int tid = threadIdx.x;
    int wv = tid >> 6, lane = tid & 63;
    int wave = rfl(blockIdx.x * 4 + wv);
    int n0 = wave * 4;
    for (int i = 0; i < 4; i++) {
        int n = n0 + i;
        int nb = n * Rr;
        int e0 = rfl(off[nb]);
        int e1 = rfl(off[nb + 1]);
        int e2 = rfl(off[nb + 2]);
        int e3 = rfl(off[nb + 3]);
        int e4 = rfl(off[nb + 4]);
        float i0 = (e1 > e0) ? 1.f / (float)(e1 - e0) : 0.f;
        float i1 = (e2 > e1) ? 1.f / (float)(e2 - e1) : 0.f;
        float i2 = (e3 > e2) ? 1.f / (float)(e3 - e2) : 0.f;
        float i3 = (e4 > e3) ? 1.f / (float)(e4 - e3) : 0.f;
        float a0 = 0.f, a1 = 0.f, a2 = 0.f, a3 = 0.f;
        int e = e0;
        for (; e + 16 <= e4; e += 16) {             // 16 loads in flight
            const int4 sA = *(const int4*)(ssrc + e);
            const int4 sB = *(const int4*)(ssrc + e + 4);
            const int4 sC = *(const int4*)(ssrc + e + 8);
            const int4 sD = *(const int4*)(ssrc + e + 12);
            float v0 = hin[(size_t)sA.x * Hd + lane];
            float v1 = hin[(size_t)sA.y * Hd + lane];
            float v2 = hin[(size_t)sA.z * Hd + lane];
            float v3 = hin[(size_t)sA.w * Hd + lane];
            float v4 = hin[(size_t)sB.x * Hd + lane];
            float v5 = hin[(size_t)sB.y * Hd + lane];
            float v6 = hin[(size_t)sB.z * Hd + lane];
            float v7 = hin[(size_t)sB.w * Hd + lane];
            float v8 = hin[(size_t)sC.x * Hd + lane];
            float v9 = hin[(size_t)sC.y * Hd + lane];
            float vA = hin[(size_t)sC.z * Hd + lane];
            float vB = hin[(size_t)sC.w * Hd + lane];
            float vC = hin[(size_t)sD.x * Hd + lane];
            float vD = hin[(size_t)sD.y * Hd + lane];
            float vE = hin[(size_t)sD.z * Hd + lane];
            float vF = hin[(size_t)sD.w * Hd + lane];
            ACCS(v0, e + 0);  ACCS(v1, e + 1);  ACCS(v2, e + 2);  ACCS(v3, e + 3);
            ACCS(v4, e + 4);  ACCS(v5, e + 5);  ACCS(v6, e + 6);  ACCS(v7, e + 7);
            ACCS(v8, e + 8);  ACCS(v9, e + 9);  ACCS(vA, e + 10); ACCS(vB, e + 11);
            ACCS(vC, e + 12); ACCS(vD, e + 13); ACCS(vE, e + 14); ACCS(vF, e + 15);
        }
        for (; e + 4 <= e4; e += 4) {
            const int4 sA = *(const int4*)(ssrc + e);
            float v0 = hin[(size_t)sA.x * Hd + lane];
            float v1 = hin[(size_t)sA.y * Hd + lane];
            float v2 = hin[(size_t)sA.z * Hd + lane];
            float v3 = hin[(size_t)sA.w * Hd + lane];
            ACCS(v0, e + 0); ACCS(v1, e + 1); ACCS(v2, e + 2); ACCS(v3, e + 3);
        }
        for (; e < e4; e++) {
            int s = rfl(ssrc[e]);
            float v = hin[(size_t)s * Hd + lane];
            ACCS(v, e);
        }
        aggR[((size_t)0 * Nn + n) * Hd + lane] = a0;   // means (inv folded)
        aggR[((size_t)1 * Nn + n) * Hd + lane] = a1;
        aggR[((size_t)2 * Nn + n) * Hd + lane] = a2;
        aggR[((size_t)3 * Nn + n) * Hd + lane] = a3;
    }
}

// ---- RGCN transform as tiled GEMM: out = relu(b + [hin|mean0..3] @ [Wroot;W]) ----
// 64 nodes x 64 cols per block; K=320 in 5 panels of 64; A+B staged in LDS.
// Each lane owns a 4x4 micro-tile; weights read once per block (62 MB total).
__global__ __launch_bounds__(256) void k_rgcn_gemm(
        const float* __restrict__ hin, const float* __restrict__ aggR,
        const float* __restrict__ W, const float* __restrict__ Wroot,
        const float* __restrict__ bias, float* __restrict__ hout) {
    __shared__ float As[64 * LDA];                  // 17 KB, padded rows
    __shared__ float Bs[64 * 64];                   // 16 KB
    int tid = threadIdx.x;
    int n0 = blockIdx.x * 64;
    int wv = tid >> 6, lane = tid & 63;
    int r = lane >> 4, c = lane & 15;
    int row_base = wv * 16 + 4 * r;                 // 4 consecutive A rows per lane
    float acc[4][4];
    #pragma unroll
    for (int i = 0; i < 4; i++)
        #pragma unroll
        for (int j = 0; j < 4; j++) acc[i][j] = 0.f;
    for (int p = 0; p < 5; p++) {
        const float* Bsrc = (p == 0) ? Wroot : (W + (size_t)(p - 1) * Hd * Hd);
        #pragma unroll
        for (int q = 0; q < 4; q++) {
            int idx = q * 256 + tid;                // 0..1023 float4 slots
            int arow = idx >> 4;
            int ac4 = idx & 15;
            int n = n0 + arow; if (n >= Nn) n = Nn - 1;
            const float* asrc = (p == 0) ? (hin + (size_t)n * Hd)
                                         : (aggR + ((size_t)(p - 1) * Nn + n) * Hd);
            *(float4*)&As[arow * LDA + ac4 * 4] = *(const float4*)(asrc + ac4 * 4);
            *(float4*)&Bs[idx * 4] = *(const float4*)(Bsrc + idx * 4);
        }
        __syncthreads();
        for (int k4 = 0; k4 < 64; k4 += 4) {
            float4 aa[4], bb[4];
            #pragma unroll
            for (int i = 0; i < 4; i++)
                aa[i] = *(float4*)&As[(row_base + i) * LDA + k4];
            #pragma unroll
            for (int kk = 0; kk < 4; kk++)
                bb[kk] = *(float4*)&Bs[(k4 + kk) * 64 + c * 4];
            #pragma unroll
            for (int i = 0; i < 4; i++) {
                acc[i][0] += aa[i].x * bb[0].x + aa[i].y * bb[1].x
                           + aa[i].z * bb[2].x + aa[i].w * bb[3].x;
                acc[i][1] += aa[i].x * bb[0].y + aa[i].y * bb[1].y
                           + aa[i].z * bb[2].y + aa[i].w * bb[3].y;
                acc[i][2] += aa[i].x * bb[0].z + aa[i].y * bb[1].z
                           + aa[i].z * bb[2].z + aa[i].w * bb[3].z;
                acc[i][3] += aa[i].x * bb[0].w + aa[i].y * bb[1].w
                           + aa[i].z * bb[2].w + aa[i].w * bb[3].w;
            }
        }
        __syncthreads();
    }
    float4 bj = *(const float4*)(bias + c * 4);
    #pragma unroll
    for (int i = 0; i < 4; i++) {
        int n = n0 + row_base + i;
        if (n < Nn) {
            float4 o;
            o.x = reluf(acc[i][0] + bj.x);
            o.y = reluf(acc[i][1] + bj.y);
            o.z = reluf(acc[i][2] + bj.z);
            o.w = reluf(acc[i][3] + bj.w);
            *(float4*)&hout[(size_t)n * Hd + c * 4] = o;
        }
    }
}

// ---- FUSED MFConv layer: 16-deep unrolled gather + degree-bucketed transform ----
__global__ __launch_bounds__(256) void k_mf_fused(
        const float* __restrict__ hin, const int* __restrict__ off,
        const int* __restrict__ ssrc, const int* __restrict__ order,
        const float* __restrict__ Wl, const float* __restrict__ bl,
        const float* __restrict__ Wr, float* __restrict__ hout, int relu_out) {
    __shared__ float lds[4][4][Hd];                 // 4 KB: [wave][node][k]
    int tid = threadIdx.x;
    int wv = tid >> 6, lane = tid & 63;
    int slot0 = rfl(blockIdx.x * 16 + wv * 4);
    int ent[4];
    #pragma unroll
    for (int i = 0; i < 4; i++) ent[i] = rfl(order[slot0 + i]);
    int d = -1;
    #pragma unroll
    for (int i = 3; i >= 0; i--) if (ent[i] >= 0) d = ent[i] >> 20;
    if (d < 0) return;
    int n[4];
    #pragma unroll
    for (int i = 0; i < 4; i++) n[i] = (ent[i] >= 0) ? (ent[i] & 0xFFFFF) : 0;
    for (int i = 0; i < 4; i++) {
        int e0 = rfl(off[n[i] * Rr]);
        int e4 = rfl(off[n[i] * Rr + Rr]);
        float p0 = 0.f, p1 = 0.f, p2 = 0.f, p3 = 0.f;
        int e = e0;
        for (; e + 16 <= e4; e += 16) {
            const int4 sA = *(const int4*)(ssrc + e);
            const int4 sB = *(const int4*)(ssrc + e + 4);
            const int4 sC = *(const int4*)(ssrc + e + 8);
            const int4 sD = *(const int4*)(ssrc + e + 12);
            p0 += hin[(size_t)sA.x * Hd + lane] + hin[(size_t)sA.y * Hd + lane]
                + hin[(size_t)sA.z * Hd + lane] + hin[(size_t)sA.w * Hd + lane];
            p1 += hin[(size_t)sB.x * Hd + lane] + hin[(size_t)sB.y * Hd + lane]
                + hin[(size_t)sB.z * Hd + lane] + hin[(size_t)sB.w * Hd + lane];
            p2 += hin[(size_t)sC.x * Hd + lane] + hin[(size_t)sC.y * Hd + lane]
                + hin[(size_t)sC.z * Hd + lane] + hin[(size_t)sC.w * Hd + lane];
            p3 += hin[(size_t)sD.x * Hd + lane] + hin[(size_t)sD.y * Hd + lane]
                + hin[(size_t)sD.z * Hd + lane] + hin[(size_t)sD.w * Hd + lane];
        }
        for (; e + 4 <= e4; e += 4) {
            const int4 sA = *(const int4*)(ssrc + e);
            p0 += hin[(size_t)sA.x * Hd + lane] + hin[(size_t)sA.y * Hd + lane]
                + hin[(size_t)sA.z * Hd + lane] + hin[(size_t)sA.w * Hd + lane];
        }
        for (; e < e4; e++) {
            int s = rfl(ssrc[e]);
            p0 += hin[(size_t)s * Hd + lane];
        }
        lds[wv][i][lane] = (p0 + p1) + (p2 + p3);
    }
    const float* wl = Wl + (size_t)d * Hd * Hd;
    const float* wr = Wr + (size_t)d * Hd * Hd;
    float acc[4] = {0.f, 0.f, 0.f, 0.f};
    for (int kc = 0; kc < Hd; kc += 4) {
        float a0 = wl[(kc + 0) * Hd + lane];
        float a1 = wl[(kc + 1) * Hd + lane];
        float a2 = wl[(kc + 2) * Hd + lane];
        float a3 = wl[(kc + 3) * Hd + lane];
        float b0 = wr[(kc + 0) * Hd + lane];
        float b1 = wr[(kc + 1) * Hd + lane];
        float b2 = wr[(kc + 2) * Hd + lane];
        float b3 = wr[(kc + 3) * Hd + lane];
        #pragma unroll
        for (int i = 0; i < 4; i++) {
            const float4 av = *(const float4*)(&lds[wv][i][kc]);
            const float4 hv = *(const float4*)(hin + (size_t)n[i] * Hd + kc);
            acc[i] += av.x * a0 + av.y * a1 + av.z * a2 + av.w * a3
                    + hv.x * b0 + hv.y * b1 + hv.z * b2 + hv.w * b3;
        }
    }
    float bb = bl[d * Hd + lane];
    #pragma unroll
    for (int i = 0; i < 4; i++)
        if (ent[i] >= 0) {
            float v = acc[i] + bb;
            hout[(size_t)n[i] * Hd + lane] = relu_out ? reluf(v) : v;
        }
}

// ---- global add pool (batch_idx is sorted -> mostly single fused atomic) ----
__global__ void k_pool(const float* __restrict__ h, const int* __restrict__ batch,
                       float* __restrict__ g) {
    int wave = rfl((blockIdx.x * 256 + threadIdx.x) >> 6);
    int lane = threadIdx.x & 63;
    int n0 = wave * 4;
    if (n0 >= Nn) return;
    int b0 = batch[n0], b1 = batch[n0 + 1], b2 = batch[n0 + 2], b3 = batch[n0 + 3];
    float v0 = h[(size_t)n0 * Hd + lane];
    float v1 = h[(size_t)(n0 + 1) * Hd + lane];
    float v2 = h[(size_t)(n0 + 2) * Hd + lane];
    float v3 = h[(size_t)(n0 + 3) * Hd + lane];
    if (b0 == b1 && b0 == b2 && b0 == b3) {
        unsafeAtomicAdd(&g[(size_t)b0 * Hd + lane], v0 + v1 + v2 + v3);
    } else {
        unsafeAtomicAdd(&g[(size_t)b0 * Hd + lane], v0);
        unsafeAtomicAdd(&g[(size_t)b1 * Hd + lane], v1);
        unsafeAtomicAdd(&g[(size_t)b2 * Hd + lane], v2);
        unsafeAtomicAdd(&g[(size_t)b3 * Hd + lane], v3);
    }
}

// ---- head: relu(g@lin1+b1)@lin2+b2, one wave per graph ----
__global__ void k_head(const float* __restrict__ g, const float* __restrict__ w1,
                       const float* __restrict__ b1, const float* __restrict__ w2,
                       const float* __restrict__ b2, float* __restrict__ out) {
    __shared__ float t[4][Hd];
    int wv = threadIdx.x >> 6;
    int lane = threadIdx.x & 63;
    int gi = blockIdx.x * 4 + wv;
    float acc = b1[lane];
    for (int k = 0; k < Hd; k++) acc += g[(size_t)gi * Hd + k] * w1[k * Hd + lane];
    t[wv][lane] = reluf(acc);
    __syncthreads();
    if (lane < Od) {
        float o = b2[lane];
        for (int k = 0; k < Hd; k++) o += t[wv][k] * w2[k * Od + lane];
        out[(size_t)gi * Od + lane] = o;
    }
}

extern "C" void kernel_launch(void* const* d_in, const int* in_sizes, int n_in,
                              void* d_out, int out_size, void* d_ws, size_t ws_size,
                              hipStream_t stream) {
    const float* x      = (const float*)d_in[0];
    const float* ea     = (const float*)d_in[1];
    const int*   eidx   = (const int*)d_in[2];
    const int*   batch  = (const int*)d_in[3];
    const float* emb    = (const float*)d_in[4];
    const float* lin1_w = (const float*)d_in[5];
    const float* lin1_b = (const float*)d_in[6];
    const float* lin2_w = (const float*)d_in[7];
    const float* lin2_b = (const float*)d_in[8];
    const float* rgcn_w[2]    = {(const float*)d_in[9],  (const float*)d_in[15]};
    const float* rgcn_root[2] = {(const float*)d_in[10], (const float*)d_in[16]};
    const float* rgcn_b[2]    = {(const float*)d_in[11], (const float*)d_in[17]};
    const float* mf_wl[2]     = {(const float*)d_in[12], (const float*)d_in[18]};
    const float* mf_bl[2]     = {(const float*)d_in[13], (const float*)d_in[19]};
    const float* mf_wr[2]     = {(const float*)d_in[14], (const float*)d_in[20]};

    char* p = (char*)d_ws;
    float* h0   = (float*)p; p += sizeof(float) * (size_t)Nn * Hd;
    float* h1   = (float*)p; p += sizeof(float) * (size_t)Nn * Hd;
    float* aggR = (float*)p; p += sizeof(float) * (size_t)Rr * Nn * Hd;
    float* gbuf = (float*)p; p += sizeof(float) * (size_t)Ng * Hd;
    int* seg    = (int*)p;   p += sizeof(int) * (size_t)Ne;
    int* ssrc   = (int*)p;   p += sizeof(int) * (size_t)Ne;
    int* cnt    = (int*)p;   p += sizeof(int) * (size_t)NSEG;   // contiguous with bcnt/bfill
    int* bcnt   = (int*)p;   p += sizeof(int) * 16;
    int* bfill  = (int*)p;   p += sizeof(int) * 16;
    int* off    = (int*)p;   p += sizeof(int) * (size_t)(NSEG + 1);
    int* fill   = (int*)p;   p += sizeof(int) * (size_t)NSEG;
    int* bsum   = (int*)p;   p += sizeof(int) * 1024;
    int* bbase  = (int*)p;   p += sizeof(int) * 16;
    int* order  = (int*)p;   p += sizeof(int) * (size_t)ORDER_SZ;

    hipMemsetAsync(cnt, 0, sizeof(int) * ((size_t)NSEG + 32), stream);
    hipMemsetAsync(order, 0xFF, sizeof(int) * (size_t)ORDER_SZ, stream);
    hipMemsetAsync(gbuf, 0, sizeof(float) * (size_t)Ng * Hd, stream);

    k_rel_seg<<<Ne / 256, 256, 0, stream>>>((const float4*)ea, eidx, seg, cnt);
    k_scan1<<<SCAN_BLK, 256, 0, stream>>>(cnt, off, bsum);
    k_scan2<<<1, 1024, 0, stream>>>(bsum);
    k_scan3<<<SCAN_BLK, 256, 0, stream>>>(off, bsum, fill);
    k_scatter<<<Ne / 256, 256, 0, stream>>>(eidx, seg, fill, ssrc);
    k_embed<<<Nn / 4, 256, 0, stream>>>(x, emb, h0);
    k_bucket_count<<<(Nn + 255) / 256, 256, 0, stream>>>(off, bcnt);
    k_bucket_prefix<<<1, 64, 0, stream>>>(bcnt, bbase);
    k_bucket_scatter<<<(Nn + 255) / 256, 256, 0, stream>>>(off, bbase, bfill, order);

    float* hin = h0;
    float* hout = h1;
    for (int b = 0; b < 2; b++) {
        k_rgcn_gather<<<NB_RG, 256, 0, stream>>>(hin, off, ssrc, aggR);
        k_rgcn_gemm<<<NB_GEMM, 256, 0, stream>>>(hin, aggR, rgcn_w[b], rgcn_root[b],
                                                 rgcn_b[b], hout);
        k_mf_fused<<<NB_MF, 256, 0, stream>>>(hout, off, ssrc, order, mf_wl[b],
                                              mf_bl[b], mf_wr[b], hin, b == 0 ? 1 : 0);
        // block output is back in hin for the next block (relu'd for b=0, raw for b=1)
    }
    k_pool<<<Nn / 16, 256, 0, stream>>>(hin, batch, gbuf);
    k_head<<<Ng / 4, 256, 0, stream>>>(gbuf, lin1_w, lin1_b, lin2_w, lin2_b, (float*)d_out);
}

// Round 10
// 453.429 us; speedup vs baseline: 1.7671x; 1.0621x over previous
//
#include <hip/hip_runtime.h>
#include <cstdint>
#include <cstddef>

#define Nn 50000
#define Ne 800000
#define Ng 1024
#define NFd 32
#define Rr 4
#define Hd 64
#define Od 16
#define MAXD 10
#define NSEG (Nn * Rr)
#define SCAN_BLK ((NSEG + 255) / 256)
#define ORDER_SZ (Nn + 48)                 // buckets padded to x4: max 11*3 pad
#define NB_MF ((ORDER_SZ + 15) / 16)       // block = 4 waves x 4 slots
#define NB_RG (Nn / 16)                    // block = 4 waves x 4 nodes
#define NB_GEMM ((Nn + 63) / 64)           // 782 blocks of 64 nodes
#define LDA 68                             // padded A leading dim (bank-conflict-free)

__device__ __forceinline__ float reluf(float v) { return v > 0.f ? v : 0.f; }
__device__ __forceinline__ int rfl(int v) { return __builtin_amdgcn_readfirstlane(v); }

// ---- per-edge relation argmax -> seg id + histogram + WITHIN-SEGMENT RANK ----
// (rank = atomicAdd return value; reused by k_scatter so it needs no atomics)
__global__ void k_rel_seg(const float4* __restrict__ ea, const int* __restrict__ eidx,
                          int* __restrict__ seg, int* __restrict__ rank,
                          int* __restrict__ cnt) {
    int e = blockIdx.x * 256 + threadIdx.x;
    if (e >= Ne) return;
    float4 a = ea[e];
    int bi = 0; float bv = a.x;
    if (a.y > bv) { bv = a.y; bi = 1; }
    if (a.z > bv) { bv = a.z; bi = 2; }
    if (a.w > bv) { bv = a.w; bi = 3; }
    int s = eidx[Ne + e] * Rr + bi;
    seg[e] = s;
    rank[e] = atomicAdd(&cnt[s], 1);
}

// ---- 3-kernel exclusive scan over cnt[NSEG] -> off[NSEG+1] ----
__global__ void k_scan1(const int* __restrict__ cnt, int* __restrict__ off,
                        int* __restrict__ bsum) {
    __shared__ int s[256];
    int t = threadIdx.x;
    int idx = blockIdx.x * 256 + t;
    int v = (idx < NSEG) ? cnt[idx] : 0;
    s[t] = v;
    __syncthreads();
    #pragma unroll
    for (int o = 1; o < 256; o <<= 1) {
        int x = (t >= o) ? s[t - o] : 0;
        __syncthreads();
        s[t] += x;
        __syncthreads();
    }
    if (idx < NSEG) off[idx] = s[t] - v;            // exclusive
    if (t == 255) bsum[blockIdx.x] = s[255];
}

__global__ void k_scan2(int* __restrict__ bsum) {
    __shared__ int s[1024];
    int t = threadIdx.x;
    int v = (t < SCAN_BLK) ? bsum[t] : 0;
    s[t] = v;
    __syncthreads();
    #pragma unroll
    for (int o = 1; o < 1024; o <<= 1) {
        int x = (t >= o) ? s[t - o] : 0;
        __syncthreads();
        s[t] += x;
        __syncthreads();
    }
    if (t < SCAN_BLK) bsum[t] = s[t] - v;           // exclusive block bases
}

__global__ void k_scan3(int* __restrict__ off, const int* __restrict__ bsum) {
    int idx = blockIdx.x * 256 + threadIdx.x;
    if (idx == 0) off[NSEG] = Ne;
    if (idx >= NSEG) return;
    off[idx] = off[idx] + bsum[blockIdx.x];
}

// ---- scatter edges into segment-sorted order: NO atomics (rank precomputed) ----
__global__ void k_scatter(const int* __restrict__ eidx, const int* __restrict__ seg,
                          const int* __restrict__ rank, const int* __restrict__ off,
                          int* __restrict__ sorted_src) {
    int e = blockIdx.x * 256 + threadIdx.x;
    if (e >= Ne) return;
    int pos = off[seg[e]] + rank[e];
    sorted_src[pos] = eidx[e];
}

// ---- embedding lookup: wave per node; writes relu'd row ----
__global__ void k_embed(const float* __restrict__ x, const float* __restrict__ emb,
                        float* __restrict__ h) {
    int wave = (blockIdx.x * 256 + threadIdx.x) >> 6;
    int lane = threadIdx.x & 63;
    if (wave >= Nn) return;
    float v = (lane < NFd) ? x[(size_t)wave * NFd + lane] : -1e30f;
    int idx = lane;
    #pragma unroll
    for (int off = 16; off >= 1; off >>= 1) {
        float ov = __shfl_down(v, off);
        int oi = __shfl_down(idx, off);
        if (ov > v || (ov == v && oi < idx)) { v = ov; idx = oi; }
    }
    idx = __shfl(idx, 0);
    h[(size_t)wave * Hd + lane] = reluf(emb[(size_t)idx * Hd + lane]);
}

// ---- degree bucketing from CSR offsets (LDS hist, 11 global atomics/block) ----
__global__ void k_bucket_count(const int* __restrict__ off, int* __restrict__ bcnt) {
    __shared__ int hist[16];
    if (threadIdx.x < 16) hist[threadIdx.x] = 0;
    __syncthreads();
    int n = blockIdx.x * 256 + threadIdx.x;
    if (n < Nn) {
        int d = min(off[n * Rr + Rr] - off[n * Rr], MAXD);
        atomicAdd(&hist[d], 1);
    }
    __syncthreads();
    if (threadIdx.x < 16) {
        int h = hist[threadIdx.x];
        if (h > 0) atomicAdd(&bcnt[threadIdx.x], h);
    }
}

__global__ void k_bucket_prefix(const int* __restrict__ bcnt, int* __restrict__ bbase) {
    if (threadIdx.x == 0 && blockIdx.x == 0) {
        int run = 0;
        for (int d = 0; d <= MAXD; d++) { bbase[d] = run; run += (bcnt[d] + 3) & ~3; }
    }
}

__global__ void k_bucket_scatter(const int* __restrict__ off, const int* __restrict__ bbase,
                                 int* __restrict__ bfill, int* __restrict__ order) {
    __shared__ int hist[16];
    __shared__ int base[16];
    if (threadIdx.x < 16) hist[threadIdx.x] = 0;
    __syncthreads();
    int n = blockIdx.x * 256 + threadIdx.x;
    int d = 0, rank = 0;
    bool valid = (n < Nn);
    if (valid) {
        d = min(off[n * Rr + Rr] - off[n * Rr], MAXD);
        rank = atomicAdd(&hist[d], 1);
    }
    __syncthreads();
    if (threadIdx.x < 16) {
        int h = hist[threadIdx.x];
        base[threadIdx.x] = (h > 0) ? atomicAdd(&bfill[threadIdx.x], h) : 0;
    }
    __syncthreads();
    if (valid) order[bbase[d] + base[d] + rank] = n | (d << 20);
}

// classify edge ee via wave-uniform boundaries -> 4 uniform scalar scales
#define ACCS(v, ee)  {                                      \
    int rr = ((ee) >= e1) + ((ee) >= e2) + ((ee) >= e3);    \
    float s0 = (rr == 0) ? i0 : 0.f;                        \
    float s1 = (rr == 1) ? i1 : 0.f;                        \
    float s2 = (rr == 2) ? i2 : 0.f;                        \
    float s3 = (rr == 3) ? i3 : 0.f;                        \
    a0 = fmaf(s0, (v), a0);                                 \
    a1 = fmaf(s1, (v), a1);                                 \
    a2 = fmaf(s2, (v), a2);                                 \
    a3 = fmaf(s3, (v), a3); }

// ---- RGCN gather: 16-deep unrolled gather -> rel-major means aggR[r][n][64] ----
__global__ __launch_bounds__(256) void k_rgcn_gather(
        const float* __restrict__ hin, const int* __restrict__ off,
        const int* __restrict__ ssrc, float* __restrict__ aggR) {
    int tid = threadIdx.x;
    int wv = tid >> 6, lane = tid & 63;
    int wave = rfl(blockIdx.x * 4 + wv);
    int n0 = wave * 4;
    for (int i = 0; i < 4; i++) {
        int n = n0 + i;
        int nb = n * Rr;
        int e0 = rfl(off[nb]);
        int e1 = rfl(off[nb + 1]);
        int e2 = rfl(off[nb + 2]);
        int e3 = rfl(off[nb + 3]);
        int e4 = rfl(off[nb + 4]);
        float i0 = (e1 > e0) ? 1.f / (float)(e1 - e0) : 0.f;
        float i1 = (e2 > e1) ? 1.f / (float)(e2 - e1) : 0.f;
        float i2 = (e3 > e2) ? 1.f / (float)(e3 - e2) : 0.f;
        float i3 = (e4 > e3) ? 1.f / (float)(e4 - e3) : 0.f;
        float a0 = 0.f, a1 = 0.f, a2 = 0.f, a3 = 0.f;
        int e = e0;
        for (; e + 16 <= e4; e += 16) {             // 16 loads in flight
            const int4 sA = *(const int4*)(ssrc + e);
            const int4 sB = *(const int4*)(ssrc + e + 4);
            const int4 sC = *(const int4*)(ssrc + e + 8);
            const int4 sD = *(const int4*)(ssrc + e + 12);
            float v0 = hin[(size_t)sA.x * Hd + lane];
            float v1 = hin[(size_t)sA.y * Hd + lane];
            float v2 = hin[(size_t)sA.z * Hd + lane];
            float v3 = hin[(size_t)sA.w * Hd + lane];
            float v4 = hin[(size_t)sB.x * Hd + lane];
            float v5 = hin[(size_t)sB.y * Hd + lane];
            float v6 = hin[(size_t)sB.z * Hd + lane];
            float v7 = hin[(size_t)sB.w * Hd + lane];
            float v8 = hin[(size_t)sC.x * Hd + lane];
            float v9 = hin[(size_t)sC.y * Hd + lane];
            float vA = hin[(size_t)sC.z * Hd + lane];
            float vB = hin[(size_t)sC.w * Hd + lane];
            float vC = hin[(size_t)sD.x * Hd + lane];
            float vD = hin[(size_t)sD.y * Hd + lane];
            float vE = hin[(size_t)sD.z * Hd + lane];
            float vF = hin[(size_t)sD.w * Hd + lane];
            ACCS(v0, e + 0);  ACCS(v1, e + 1);  ACCS(v2, e + 2);  ACCS(v3, e + 3);
            ACCS(v4, e + 4);  ACCS(v5, e + 5);  ACCS(v6, e + 6);  ACCS(v7, e + 7);
            ACCS(v8, e + 8);  ACCS(v9, e + 9);  ACCS(vA, e + 10); ACCS(vB, e + 11);
            ACCS(vC, e + 12); ACCS(vD, e + 13); ACCS(vE, e + 14); ACCS(vF, e + 15);
        }
        for (; e + 4 <= e4; e += 4) {
            const int4 sA = *(const int4*)(ssrc + e);
            float v0 = hin[(size_t)sA.x * Hd + lane];
            float v1 = hin[(size_t)sA.y * Hd + lane];
            float v2 = hin[(size_t)sA.z * Hd + lane];
            float v3 = hin[(size_t)sA.w * Hd + lane];
            ACCS(v0, e + 0); ACCS(v1, e + 1); ACCS(v2, e + 2); ACCS(v3, e + 3);
        }
        for (; e < e4; e++) {
            int s = rfl(ssrc[e]);
            float v = hin[(size_t)s * Hd + lane];
            ACCS(v, e);
        }
        aggR[((size_t)0 * Nn + n) * Hd + lane] = a0;   // means (inv folded)
        aggR[((size_t)1 * Nn + n) * Hd + lane] = a1;
        aggR[((size_t)2 * Nn + n) * Hd + lane] = a2;
        aggR[((size_t)3 * Nn + n) * Hd + lane] = a3;
    }
}

// ---- RGCN transform as tiled GEMM: out = relu(b + [hin|mean0..3] @ [Wroot;W]) ----
__global__ __launch_bounds__(256) void k_rgcn_gemm(
        const float* __restrict__ hin, const float* __restrict__ aggR,
        const float* __restrict__ W, const float* __restrict__ Wroot,
        const float* __restrict__ bias, float* __restrict__ hout) {
    __shared__ float As[64 * LDA];                  // 17 KB, padded rows
    __shared__ float Bs[64 * 64];                   // 16 KB
    int tid = threadIdx.x;
    int n0 = blockIdx.x * 64;
    int wv = tid >> 6, lane = tid & 63;
    int r = lane >> 4, c = lane & 15;
    int row_base = wv * 16 + 4 * r;                 // 4 consecutive A rows per lane
    float acc[4][4];
    #pragma unroll
    for (int i = 0; i < 4; i++)
        #pragma unroll
        for (int j = 0; j < 4; j++) acc[i][j] = 0.f;
    for (int p = 0; p < 5; p++) {
        const float* Bsrc = (p == 0) ? Wroot : (W + (size_t)(p - 1) * Hd * Hd);
        #pragma unroll
        for (int q = 0; q < 4; q++) {
            int idx = q * 256 + tid;                // 0..1023 float4 slots
            int arow = idx >> 4;
            int ac4 = idx & 15;
            int n = n0 + arow; if (n >= Nn) n = Nn - 1;
            const float* asrc = (p == 0) ? (hin + (size_t)n * Hd)
                                         : (aggR + ((size_t)(p - 1) * Nn + n) * Hd);
            *(float4*)&As[arow * LDA + ac4 * 4] = *(const float4*)(asrc + ac4 * 4);
            *(float4*)&Bs[idx * 4] = *(const float4*)(Bsrc + idx * 4);
        }
        __syncthreads();
        for (int k4 = 0; k4 < 64; k4 += 4) {
            float4 aa[4], bb[4];
            #pragma unroll
            for (int i = 0; i < 4; i++)
                aa[i] = *(float4*)&As[(row_base + i) * LDA + k4];
            #pragma unroll
            for (int kk = 0; kk < 4; kk++)
                bb[kk] = *(float4*)&Bs[(k4 + kk) * 64 + c * 4];
            #pragma unroll
            for (int i = 0; i < 4; i++) {
                acc[i][0] += aa[i].x * bb[0].x + aa[i].y * bb[1].x
                           + aa[i].z * bb[2].x + aa[i].w * bb[3].x;
                acc[i][1] += aa[i].x * bb[0].y + aa[i].y * bb[1].y
                           + aa[i].z * bb[2].y + aa[i].w * bb[3].y;
                acc[i][2] += aa[i].x * bb[0].z + aa[i].y * bb[1].z
                           + aa[i].z * bb[2].z + aa[i].w * bb[3].z;
                acc[i][3] += aa[i].x * bb[0].w + aa[i].y * bb[1].w
                           + aa[i].z * bb[2].w + aa[i].w * bb[3].w;
            }
        }
        __syncthreads();
    }
    float4 bj = *(const float4*)(bias + c * 4);
    #pragma unroll
    for (int i = 0; i < 4; i++) {
        int n = n0 + row_base + i;
        if (n < Nn) {
            float4 o;
            o.x = reluf(acc[i][0] + bj.x);
            o.y = reluf(acc[i][1] + bj.y);
            o.z = reluf(acc[i][2] + bj.z);
            o.w = reluf(acc[i][3] + bj.w);
            *(float4*)&hout[(size_t)n * Hd + c * 4] = o;
        }
    }
}

// ---- FUSED MFConv layer: 16-deep unrolled gather + degree-bucketed transform ----
__global__ __launch_bounds__(256) void k_mf_fused(
        const float* __restrict__ hin, const int* __restrict__ off,
        const int* __restrict__ ssrc, const int* __restrict__ order,
        const float* __restrict__ Wl, const float* __restrict__ bl,
        const float* __restrict__ Wr, float* __restrict__ hout, int relu_out) {
    __shared__ float lds[4][4][Hd];                 // 4 KB: [wave][node][k]
    int tid = threadIdx.x;
    int wv = tid >> 6, lane = tid & 63;
    int slot0 = rfl(blockIdx.x * 16 + wv * 4);
    int ent[4];
    #pragma unroll
    for (int i = 0; i < 4; i++) ent[i] = rfl(order[slot0 + i]);
    int d = -1;
    #pragma unroll
    for (int i = 3; i >= 0; i--) if (ent[i] >= 0) d = ent[i] >> 20;
    if (d < 0) return;
    int n[4];
    #pragma unroll
    for (int i = 0; i < 4; i++) n[i] = (ent[i] >= 0) ? (ent[i] & 0xFFFFF) : 0;
    for (int i = 0; i < 4; i++) {
        int e0 = rfl(off[n[i] * Rr]);
        int e4 = rfl(off[n[i] * Rr + Rr]);
        float p0 = 0.f, p1 = 0.f, p2 = 0.f, p3 = 0.f;
        int e = e0;
        for (; e + 16 <= e4; e += 16) {
            const int4 sA = *(const int4*)(ssrc + e);
            const int4 sB = *(const int4*)(ssrc + e + 4);
            const int4 sC = *(const int4*)(ssrc + e + 8);
            const int4 sD = *(const int4*)(ssrc + e + 12);
            p0 += hin[(size_t)sA.x * Hd + lane] + hin[(size_t)sA.y * Hd + lane]
                + hin[(size_t)sA.z * Hd + lane] + hin[(size_t)sA.w * Hd + lane];
            p1 += hin[(size_t)sB.x * Hd + lane] + hin[(size_t)sB.y * Hd + lane]
                + hin[(size_t)sB.z * Hd + lane] + hin[(size_t)sB.w * Hd + lane];
            p2 += hin[(size_t)sC.x * Hd + lane] + hin[(size_t)sC.y * Hd + lane]
                + hin[(size_t)sC.z * Hd + lane] + hin[(size_t)sC.w * Hd + lane];
            p3 += hin[(size_t)sD.x * Hd + lane] + hin[(size_t)sD.y * Hd + lane]
                + hin[(size_t)sD.z * Hd + lane] + hin[(size_t)sD.w * Hd + lane];
        }
        for (; e + 4 <= e4; e += 4) {
            const int4 sA = *(const int4*)(ssrc + e);
            p0 += hin[(size_t)sA.x * Hd + lane] + hin[(size_t)sA.y * Hd + lane]
                + hin[(size_t)sA.z * Hd + lane] + hin[(size_t)sA.w * Hd + lane];
        }
        for (; e < e4; e++) {
            int s = rfl(ssrc[e]);
            p0 += hin[(size_t)s * Hd + lane];
        }
        lds[wv][i][lane] = (p0 + p1) + (p2 + p3);
    }
    const float* wl = Wl + (size_t)d * Hd * Hd;
    const float* wr = Wr + (size_t)d * Hd * Hd;
    float acc[4] = {0.f, 0.f, 0.f, 0.f};
    for (int kc = 0; kc < Hd; kc += 4) {
        float a0 = wl[(kc + 0) * Hd + lane];
        float a1 = wl[(kc + 1) * Hd + lane];
        float a2 = wl[(kc + 2) * Hd + lane];
        float a3 = wl[(kc + 3) * Hd + lane];
        float b0 = wr[(kc + 0) * Hd + lane];
        float b1 = wr[(kc + 1) * Hd + lane];
        float b2 = wr[(kc + 2) * Hd + lane];
        float b3 = wr[(kc + 3) * Hd + lane];
        #pragma unroll
        for (int i = 0; i < 4; i++) {
            const float4 av = *(const float4*)(&lds[wv][i][kc]);
            const float4 hv = *(const float4*)(hin + (size_t)n[i] * Hd + kc);
            acc[i] += av.x * a0 + av.y * a1 + av.z * a2 + av.w * a3
                    + hv.x * b0 + hv.y * b1 + hv.z * b2 + hv.w * b3;
        }
    }
    float bb = bl[d * Hd + lane];
    #pragma unroll
    for (int i = 0; i < 4; i++)
        if (ent[i] >= 0) {
            float v = acc[i] + bb;
            hout[(size_t)n[i] * Hd + lane] = relu_out ? reluf(v) : v;
        }
}

// ---- global add pool (batch_idx is sorted -> mostly single fused atomic) ----
__global__ void k_pool(const float* __restrict__ h, const int* __restrict__ batch,
                       float* __restrict__ g) {
    int wave = rfl((blockIdx.x * 256 + threadIdx.x) >> 6);
    int lane = threadIdx.x & 63;
    int n0 = wave * 4;
    if (n0 >= Nn) return;
    int b0 = batch[n0], b1 = batch[n0 + 1], b2 = batch[n0 + 2], b3 = batch[n0 + 3];
    float v0 = h[(size_t)n0 * Hd + lane];
    float v1 = h[(size_t)(n0 + 1) * Hd + lane];
    float v2 = h[(size_t)(n0 + 2) * Hd + lane];
    float v3 = h[(size_t)(n0 + 3) * Hd + lane];
    if (b0 == b1 && b0 == b2 && b0 == b3) {
        unsafeAtomicAdd(&g[(size_t)b0 * Hd + lane], v0 + v1 + v2 + v3);
    } else {
        unsafeAtomicAdd(&g[(size_t)b0 * Hd + lane], v0);
        unsafeAtomicAdd(&g[(size_t)b1 * Hd + lane], v1);
        unsafeAtomicAdd(&g[(size_t)b2 * Hd + lane], v2);
        unsafeAtomicAdd(&g[(size_t)b3 * Hd + lane], v3);
    }
}

// ---- head: relu(g@lin1+b1)@lin2+b2, one wave per graph ----
__global__ void k_head(const float* __restrict__ g, const float* __restrict__ w1,
                       const float* __restrict__ b1, const float* __restrict__ w2,
                       const float* __restrict__ b2, float* __restrict__ out) {
    __shared__ float t[4][Hd];
    int wv = threadIdx.x >> 6;
    int lane = threadIdx.x & 63;
    int gi = blockIdx.x * 4 + wv;
    float acc = b1[lane];
    for (int k = 0; k < Hd; k++) acc += g[(size_t)gi * Hd + k] * w1[k * Hd + lane];
    t[wv][lane] = reluf(acc);
    __syncthreads();
    if (lane < Od) {
        float o = b2[lane];
        for (int k = 0; k < Hd; k++) o += t[wv][k] * w2[k * Od + lane];
        out[(size_t)gi * Od + lane] = o;
    }
}

extern "C" void kernel_launch(void* const* d_in, const int* in_sizes, int n_in,
                              void* d_out, int out_size, void* d_ws, size_t ws_size,
                              hipStream_t stream) {
    const float* x      = (const float*)d_in[0];
    const float* ea     = (const float*)d_in[1];
    const int*   eidx   = (const int*)d_in[2];
    const int*   batch  = (const int*)d_in[3];
    const float* emb    = (const float*)d_in[4];
    const float* lin1_w = (const float*)d_in[5];
    const float* lin1_b = (const float*)d_in[6];
    const float* lin2_w = (const float*)d_in[7];
    const float* lin2_b = (const float*)d_in[8];
    const float* rgcn_w[2]    = {(const float*)d_in[9],  (const float*)d_in[15]};
    const float* rgcn_root[2] = {(const float*)d_in[10], (const float*)d_in[16]};
    const float* rgcn_b[2]    = {(const float*)d_in[11], (const float*)d_in[17]};
    const float* mf_wl[2]     = {(const float*)d_in[12], (const float*)d_in[18]};
    const float* mf_bl[2]     = {(const float*)d_in[13], (const float*)d_in[19]};
    const float* mf_wr[2]     = {(const float*)d_in[14], (const float*)d_in[20]};

    char* p = (char*)d_ws;
    float* h0   = (float*)p; p += sizeof(float) * (size_t)Nn * Hd;
    float* h1   = (float*)p; p += sizeof(float) * (size_t)Nn * Hd;
    float* aggR = (float*)p; p += sizeof(float) * (size_t)Rr * Nn * Hd;
    float* gbuf = (float*)p; p += sizeof(float) * (size_t)Ng * Hd;
    int* seg    = (int*)p;   p += sizeof(int) * (size_t)Ne;
    int* rank   = (int*)p;   p += sizeof(int) * (size_t)Ne;
    int* ssrc   = (int*)p;   p += sizeof(int) * (size_t)Ne;
    int* cnt    = (int*)p;   p += sizeof(int) * (size_t)NSEG;   // contiguous with bcnt/bfill
    int* bcnt   = (int*)p;   p += sizeof(int) * 16;
    int* bfill  = (int*)p;   p += sizeof(int) * 16;
    int* off    = (int*)p;   p += sizeof(int) * (size_t)(NSEG + 1);
    int* bsum   = (int*)p;   p += sizeof(int) * 1024;
    int* bbase  = (int*)p;   p += sizeof(int) * 16;
    int* order  = (int*)p;   p += sizeof(int) * (size_t)ORDER_SZ;

    hipMemsetAsync(cnt, 0, sizeof(int) * ((size_t)NSEG + 32), stream);
    hipMemsetAsync(order, 0xFF, sizeof(int) * (size_t)ORDER_SZ, stream);
    hipMemsetAsync(gbuf, 0, sizeof(float) * (size_t)Ng * Hd, stream);

    k_rel_seg<<<Ne / 256, 256, 0, stream>>>((const float4*)ea, eidx, seg, rank, cnt);
    k_scan1<<<SCAN_BLK, 256, 0, stream>>>(cnt, off, bsum);
    k_scan2<<<1, 1024, 0, stream>>>(bsum);
    k_scan3<<<SCAN_BLK, 256, 0, stream>>>(off, bsum);
    k_scatter<<<Ne / 256, 256, 0, stream>>>(eidx, seg, rank, off, ssrc);
    k_embed<<<Nn / 4, 256, 0, stream>>>(x, emb, h0);
    k_bucket_count<<<(Nn + 255) / 256, 256, 0, stream>>>(off, bcnt);
    k_bucket_prefix<<<1, 64, 0, stream>>>(bcnt, bbase);
    k_bucket_scatter<<<(Nn + 255) / 256, 256, 0, stream>>>(off, bbase, bfill, order);

    float* hin = h0;
    float* hout = h1;
    for (int b = 0; b < 2; b++) {
        k_rgcn_gather<<<NB_RG, 256, 0, stream>>>(hin, off, ssrc, aggR);
        k_rgcn_gemm<<<NB_GEMM, 256, 0, stream>>>(hin, aggR, rgcn_w[b], rgcn_root[b],
                                                 rgcn_b[b], hout);
        k_mf_fused<<<NB_MF, 256, 0, stream>>>(hout, off, ssrc, order, mf_wl[b],
                                              mf_bl[b], mf_wr[b], hin, b == 0 ? 1 : 0);
        // block output is back in hin for the next block (relu'd for b=0, raw for b=1)
    }
    k_pool<<<Nn / 16, 256, 0, stream>>>(hin, batch, gbuf);
    k_head<<<Ng / 4, 256, 0, stream>>>(gbuf, lin1_w, lin1_b, lin2_w, lin2_b, (float*)d_out);
}